// Round 1
// baseline (265.666 us; speedup 1.0000x reference)
//
#include <hip/hip_runtime.h>

// MassConservingLSTMCell — round 6: occupancy fix for k_heavy.
// R5 was latency-bound at 2 waves/SIMD (acc+outa=128 regs alone -> ~210 unified
// regs/wave -> occupancy cap). R6 halves the wave tile to 4mt x 2nt and widens
// the block to 16 waves (2 rh x 8 cq, 1024 thr), grid unchanged (8 Mb x 32 ug).
// Total regs/wave ~125 -> __launch_bounds__(1024,4) -> 4 waves/SIMD (2x TLP).
// B-from-L2 traffic per MFMA unchanged (nt shrank, not mt); LDS A-reads double
// but LDS has 3x headroom. Epilogue/atomics/k_prep/k_post identical to R5.
//
// B=1024, U=256, F=31, D=288 (9 k-chunks of 32).

#define EPS_L1 1e-7f

constexpr int BB  = 1024;
constexpr int U   = 256;
constexpr int F   = 31;
constexpr int D   = 1 + U + F;      // 288
constexpr int NBV = BB * U;         // 262144
constexpr int NCH = D / 32;         // 9
constexpr int UIMGB = NCH * 16384;  // 147456 B per u-slice B-image
constexpr size_t WTB_BYTES  = (size_t)258 * UIMGB;
constexpr size_t FEAT_BYTES = (size_t)BB * D * 2;
constexpr int PITCH = 260;

typedef float f32x4 __attribute__((ext_vector_type(4)));
typedef short bf16x8 __attribute__((ext_vector_type(8)));

__device__ __forceinline__ unsigned f2bf(float x) {
  union { float f; unsigned u; } v; v.f = x;
  unsigned r = v.u + 0x7FFFu + ((v.u >> 16) & 1u);
  return r >> 16;
}

#define GLDS16(gp, lp)                                                        \
  __builtin_amdgcn_global_load_lds(                                          \
      (const __attribute__((address_space(1))) void*)(gp),                   \
      (__attribute__((address_space(3))) void*)(lp), 16, 0, 0)

#define MFMA16(a, b, c) __builtin_amdgcn_mfma_f32_16x16x32_bf16((a), (b), (c), 0, 0, 0)

// ---------------------------------------------------------------- k_prep
__global__ __launch_bounds__(256) void k_prep(
    const float* __restrict__ lc, const float* __restrict__ p,
    const float* __restrict__ other,
    const float* __restrict__ Wi, const float* __restrict__ Wr,
    const float* __restrict__ Wo,
    short* __restrict__ WtB, short* __restrict__ featImg,
    float* __restrict__ cell_sys) {
  __shared__ short lds[2][32 * PITCH];
  __shared__ float inv_s[64];
  const int bid = blockIdx.x, t = threadIdx.x;

  if (bid < 774) {
    // ---- weight transform: u-slice bid/3, chunks [3*(bid%3), +3)
    const int u = bid / 3, part = bid % 3;
    const float* src; long ld;
    if (u < 256)       { src = Wr + (size_t)u * 256; ld = 65536; }
    else if (u == 256) { src = Wi; ld = 256; }
    else               { src = Wo; ld = 256; }
    short* dst = WtB + (size_t)u * 73728;
    const int lane = t & 63, wave = t >> 6;
    const int g = lane >> 4, l15 = lane & 15;

#pragma unroll
    for (int cc = 0; cc < 3; ++cc) {
      const int c = part * 3 + cc;
      short* buf = lds[cc & 1];
      // phase 1: coalesced reads (1KB per wave-instruction)
#pragma unroll
      for (int i = 0; i < 8; ++i) {
        const int f = i * 256 + t;
        const int row = f >> 6, col4 = f & 63;
        const float4 v = *(const float4*)(src + (size_t)(c * 32 + row) * ld + col4 * 4);
        const unsigned lo = f2bf(v.x) | (f2bf(v.y) << 16);
        const unsigned hi = f2bf(v.z) | (f2bf(v.w) << 16);
        unsigned* wp = (unsigned*)&buf[row * PITCH + col4 * 4];
        wp[0] = lo; wp[1] = hi;
      }
      __syncthreads();
      // phase 2: fragment gather, 1KB-contiguous stores
#pragma unroll
      for (int i = 0; i < 4; ++i) {
        const int n0 = wave * 4 + i;
        bf16x8 h;
#pragma unroll
        for (int j = 0; j < 8; ++j)
          h[j] = buf[(g * 8 + j) * PITCH + n0 * 16 + l15];
        *(bf16x8*)(dst + (size_t)(c * 16 + n0) * 512 + lane * 8) = h;
      }
      __syncthreads();
    }
  } else if (bid < 790) {
    // ---- features -> A fragment image (64-row block mb)
    const int mb = bid - 774;
    const int b0 = mb * 64;
    const int row = t >> 2, q = t & 3;
    const float4* lp = (const float4*)(lc + (size_t)(b0 + row) * 256 + q * 64);
    float s = 0.f;
#pragma unroll
    for (int j = 0; j < 16; ++j) {
      const float4 v = lp[j];
      s += fabsf(v.x) + fabsf(v.y) + fabsf(v.z) + fabsf(v.w);
    }
    s += __shfl_xor(s, 1, 64);
    s += __shfl_xor(s, 2, 64);
    if (q == 0) inv_s[row] = 1.f / (s + EPS_L1);
    __syncthreads();
#pragma unroll
    for (int i = 0; i < 9; ++i) {
      const int idx = i * 256 + t;
      const int reg = idx >> 6, l = idx & 63;
      const int c = reg >> 2, mt = reg & 3;
      const int lrow = mt * 16 + (l & 15);
      const int grow = b0 + lrow;
      const int k0 = c * 32 + (l >> 4) * 8;
      bf16x8 h;
#pragma unroll
      for (int j = 0; j < 8; ++j) {
        const int k = k0 + j;
        float v;
        if (k == 0) v = p[grow];
        else if (k <= 256) v = lc[(size_t)grow * 256 + (k - 1)] * inv_s[lrow];
        else v = other[(size_t)grow * 31 + (k - 257)];
        h[j] = (short)f2bf(v);
      }
      *(bf16x8*)(featImg + (size_t)mb * 18432 + (size_t)reg * 512 + l * 8) = h;
    }
  } else {
    // ---- zero cell_sys
    float4* cs4 = (float4*)cell_sys;
    const int base = (bid - 790) * 8192 + t;
    const float4 z = {0.f, 0.f, 0.f, 0.f};
#pragma unroll
    for (int k2 = 0; k2 < 32; ++k2) cs4[base + k2 * 256] = z;
  }
}

// ---------------------------------------------------------------- k_heavyR6
// 256 blocks (8 Mb x 32 ug), 1024 thr, 16 waves = 2 rh x 8 cq,
// wave tile 4mt x 2nt. ~125 unified regs/wave -> 4 waves/SIMD.
__global__ __launch_bounds__(1024, 4) void k_heavyR6(
    const short* __restrict__ featImg, const short* __restrict__ WtB,
    const float* __restrict__ lc, const float* __restrict__ br,
    float* __restrict__ cell_sys) {
  __shared__ short aT[36864];          // 73728 B: [rh][c][mt][1KB]
  __shared__ float rsum[2][128][8];    // [par][row][cq]  (8 KB)
  __shared__ float lcs[2][128];

  const int t = threadIdx.x, lane = t & 63, wave = t >> 6;
  const int cq = wave & 7, rh = wave >> 3;
  const int quad = lane >> 4, l15 = lane & 15;
  const int bid = blockIdx.x;
  const int Mb = bid >> 5, ug = bid & 31;   // ug%8 = XCD pin
  const int b0 = Mb * 128, u0 = ug * 8;

  // stage A (two 64-row images, linear; wave-uniform guard on tail chunk)
  {
    const char* gA = (const char*)featImg + (size_t)Mb * 73728;
    char* lA = (char*)aT;
#pragma unroll
    for (int i = 0; i < 5; ++i) {
      const int off = i * 16384 + t * 16;
      if (off < 73728) GLDS16(gA + off, lA + off);
    }
  }

  const char* aB = (const char*)aT + rh * 36864 + lane * 16;   // + c*4096 + m*1024
  const char* bB = (const char*)WtB + (size_t)u0 * UIMGB + cq * 2048 + lane * 16;

  f32x4 acc[4][2], outa[4][2];
#pragma unroll
  for (int m = 0; m < 4; ++m)
#pragma unroll
    for (int n = 0; n < 2; ++n)
#pragma unroll
      for (int r = 0; r < 4; ++r) { acc[m][n][r] = 0.f; outa[m][n][r] = 0.f; }

  bf16x8 afr[2][4], bfr[2][2];

  // B c=0 prefetch (before barrier; barrier drains it harmlessly)
#pragma unroll
  for (int n = 0; n < 2; ++n) bfr[0][n] = *(const bf16x8*)(bB + n * 1024);

  __syncthreads();   // A resident

#pragma unroll
  for (int m = 0; m < 4; ++m) afr[0][m] = *(const bf16x8*)(aB + m * 1024);

  for (int uu = 0; uu < 8; ++uu) {
    const int u = u0 + uu;
    float bv[2];

#pragma unroll
    for (int c = 0; c < 9; ++c) {
      if (c == 0) {
#pragma unroll
        for (int n = 0; n < 2; ++n)
          bv[n] = br[(size_t)u * 256 + cq * 32 + n * 16 + l15];
        if (t < 128) lcs[uu & 1][t] = lc[(size_t)(b0 + t) * 256 + u];
      }
      // dist-1 prefetch of c+1 (A from LDS, B from global/L2)
      if (c < 8) {
#pragma unroll
        for (int n = 0; n < 2; ++n)
          bfr[(c + 1) & 1][n] = *(const bf16x8*)(bB + (c + 1) * 16384 + n * 1024);
#pragma unroll
        for (int m = 0; m < 4; ++m)
          afr[(c + 1) & 1][m] = *(const bf16x8*)(aB + (c + 1) * 4096 + m * 1024);
      }
#pragma unroll
      for (int m = 0; m < 4; ++m)
#pragma unroll
        for (int n = 0; n < 2; ++n)
          acc[m][n] = MFMA16(afr[c & 1][m], bfr[c & 1][n], acc[m][n]);
    }
    bB += UIMGB;

    // next-u c=0 prefetch issued early; latency hides under the epilogue.
    // (Last u reads the u0+8 image — always inside WtB's 258 slices; unused.)
#pragma unroll
    for (int n = 0; n < 2; ++n) bfr[0][n] = *(const bf16x8*)(bB + n * 1024);
#pragma unroll
    for (int m = 0; m < 4; ++m) afr[0][m] = *(const bf16x8*)(aB + m * 1024);

    // ---- epilogue for u: bias+relu (into acc), cross-wave rownorm, accumulate
    const int ub = uu & 1;
    float sm[4][4];
#pragma unroll
    for (int m = 0; m < 4; ++m)
#pragma unroll
      for (int r = 0; r < 4; ++r) {
        float sv = 0.f;
#pragma unroll
        for (int n = 0; n < 2; ++n) {
          const float rv = fmaxf(acc[m][n][r] + bv[n], 0.f);
          acc[m][n][r] = rv;
          sv += rv;
        }
        sm[m][r] = sv;
      }
#pragma unroll
    for (int msk = 1; msk < 16; msk <<= 1)
#pragma unroll
      for (int m = 0; m < 4; ++m)
#pragma unroll
        for (int r = 0; r < 4; ++r)
          sm[m][r] += __shfl_xor(sm[m][r], msk, 64);
    if (l15 == 0) {
#pragma unroll
      for (int m = 0; m < 4; ++m)
#pragma unroll
        for (int r = 0; r < 4; ++r)
          rsum[ub][rh * 64 + m * 16 + quad * 4 + r][cq] = sm[m][r];
    }
    __syncthreads();
#pragma unroll
    for (int m = 0; m < 4; ++m)
#pragma unroll
      for (int r = 0; r < 4; ++r) {
        const int row = rh * 64 + m * 16 + quad * 4 + r;
        const float4 ra = *(const float4*)&rsum[ub][row][0];
        const float4 rb = *(const float4*)&rsum[ub][row][4];
        const float tot = ((ra.x + ra.y) + (ra.z + ra.w)) +
                          ((rb.x + rb.y) + (rb.z + rb.w));
        const float alpha = lcs[ub][row] * __builtin_amdgcn_rcpf(tot);
#pragma unroll
        for (int n = 0; n < 2; ++n) {
          outa[m][n][r] = fmaf(alpha, acc[m][n][r], outa[m][n][r]);
          acc[m][n][r] = 0.f;
        }
      }
  }

#pragma unroll
  for (int m = 0; m < 4; ++m)
#pragma unroll
    for (int r = 0; r < 4; ++r) {
      const int grow = b0 + rh * 64 + m * 16 + quad * 4 + r;
#pragma unroll
      for (int n = 0; n < 2; ++n)
        atomicAdd(&cell_sys[(size_t)grow * 256 + cq * 32 + n * 16 + l15],
                  outa[m][n][r]);
    }
}

// ---------------------------------------------------------------- k_post
// 16 blocks x 512: gates MFMA (64 rows/block, ig+og in regs) + final combine.
__global__ __launch_bounds__(512, 2) void k_post(
    const short* __restrict__ featImg, const short* __restrict__ WtB,
    const float* __restrict__ bi, const float* __restrict__ bo,
    const float* __restrict__ p, const float* __restrict__ cell_sys,
    float* __restrict__ dout) {
  __shared__ short aT[18432];
  __shared__ float rsum[64][12];
  __shared__ float ps[64];

  const int t = threadIdx.x, lane = t & 63, cg = t >> 6;
  const int quad = lane >> 4, l15 = lane & 15;
  const int mb = blockIdx.x, b0 = mb * 64;

  {
    const char* gsrc = (const char*)featImg + (size_t)mb * 36864;
    char* lbase = (char*)aT;
#pragma unroll
    for (int i = 0; i < 5; ++i) {
      if (i * 8 + cg < 36) {
        const int off = i * 8192 + t * 16;
        GLDS16(gsrc + off, lbase + off);
      }
    }
  }
  if (t < 64) ps[t] = p[b0 + t];

  f32x4 acc[4][2];
#pragma unroll
  for (int mt = 0; mt < 4; ++mt)
#pragma unroll
    for (int n = 0; n < 2; ++n)
#pragma unroll
      for (int r = 0; r < 4; ++r) acc[mt][n][r] = 0.f;

  const char* bptr = (const char*)WtB + (size_t)256 * UIMGB + cg * 2048 + lane * 16;
  bf16x8 cb0 = *(const bf16x8*)(bptr);
  bf16x8 cb1 = *(const bf16x8*)(bptr + 1024);
  bf16x8 nb0 = *(const bf16x8*)(bptr + 16384);
  bf16x8 nb1 = *(const bf16x8*)(bptr + 16384 + 1024);
  bptr += 32768;

  __syncthreads();

  float ig0[4][4], ig1[4][4], og0[4][4], og1[4][4];

#pragma unroll
  for (int g = 0; g < 2; ++g) {
    const float* bias = (g == 0) ? bi : bo;
    const float bv0 = bias[cg * 32 + l15];
    const float bv1 = bias[cg * 32 + 16 + l15];
#pragma unroll
    for (int c = 0; c < 9; ++c) {
      const bf16x8 pb0 = *(const bf16x8*)(bptr);
      const bf16x8 pb1 = *(const bf16x8*)(bptr + 1024);
      bptr += 16384;
      const char* ab = (const char*)aT + c * 4096 + lane * 16;
      const bf16x8 a0 = *(const bf16x8*)(ab);
      const bf16x8 a1 = *(const bf16x8*)(ab + 1024);
      const bf16x8 a2 = *(const bf16x8*)(ab + 2048);
      const bf16x8 a3 = *(const bf16x8*)(ab + 3072);
      acc[0][0] = MFMA16(a0, cb0, acc[0][0]);
      acc[0][1] = MFMA16(a0, cb1, acc[0][1]);
      acc[1][0] = MFMA16(a1, cb0, acc[1][0]);
      acc[1][1] = MFMA16(a1, cb1, acc[1][1]);
      acc[2][0] = MFMA16(a2, cb0, acc[2][0]);
      acc[2][1] = MFMA16(a2, cb1, acc[2][1]);
      acc[3][0] = MFMA16(a3, cb0, acc[3][0]);
      acc[3][1] = MFMA16(a3, cb1, acc[3][1]);
      cb0 = nb0; cb1 = nb1; nb0 = pb0; nb1 = pb1;
    }

#pragma unroll
    for (int mt = 0; mt < 4; ++mt)
#pragma unroll
      for (int r = 0; r < 4; ++r) {
        const float v0 = 1.f / (1.f + __expf(-(acc[mt][0][r] + bv0)));
        const float v1 = 1.f / (1.f + __expf(-(acc[mt][1][r] + bv1)));
        if (g == 0) { ig0[mt][r] = v0; ig1[mt][r] = v1; }
        else        { og0[mt][r] = v0; og1[mt][r] = v1; }
        acc[mt][0][r] = 0.f;
        acc[mt][1][r] = 0.f;
      }

    if (g == 0) {
      float sm[4][4];
#pragma unroll
      for (int mt = 0; mt < 4; ++mt)
#pragma unroll
        for (int r = 0; r < 4; ++r) sm[mt][r] = ig0[mt][r] + ig1[mt][r];
#pragma unroll
      for (int msk = 1; msk < 16; msk <<= 1)
#pragma unroll
        for (int mt = 0; mt < 4; ++mt)
#pragma unroll
          for (int r = 0; r < 4; ++r)
            sm[mt][r] += __shfl_xor(sm[mt][r], msk, 64);
      if (l15 == 0) {
#pragma unroll
        for (int mt = 0; mt < 4; ++mt)
#pragma unroll
          for (int r = 0; r < 4; ++r)
            rsum[mt * 16 + quad * 4 + r][cg] = sm[mt][r];
      }
      __syncthreads();
#pragma unroll
      for (int mt = 0; mt < 4; ++mt)
#pragma unroll
        for (int r = 0; r < 4; ++r) {
          const int row = mt * 16 + quad * 4 + r;
          const float4 ra = *(const float4*)&rsum[row][0];
          const float4 rb = *(const float4*)&rsum[row][4];
          const float inv = 1.f / (((ra.x + ra.y) + (ra.z + ra.w)) +
                                   ((rb.x + rb.y) + (rb.z + rb.w)));
          ig0[mt][r] *= inv;
          ig1[mt][r] *= inv;
        }
    }
  }

#pragma unroll
  for (int mt = 0; mt < 4; ++mt)
#pragma unroll
    for (int r = 0; r < 4; ++r) {
      const int row = mt * 16 + quad * 4 + r;
      const float pr = ps[row];
      const size_t base = (size_t)(b0 + row) * 256 + cg * 32 + l15;
      {
        const float cand = fmaf(ig0[mt][r], pr, cell_sys[base]);
        dout[base] = (1.f - og0[mt][r]) * cand;
        dout[NBV + base] = og0[mt][r] * cand;
      }
      {
        const float cand = fmaf(ig1[mt][r], pr, cell_sys[base + 16]);
        dout[base + 16] = (1.f - og1[mt][r]) * cand;
        dout[NBV + base + 16] = og1[mt][r] * cand;
      }
    }
}

// ---------------------------------------------------------------- launch
extern "C" void kernel_launch(void* const* d_in, const int* in_sizes, int n_in,
                              void* d_out, int out_size, void* d_ws, size_t ws_size,
                              hipStream_t stream) {
  const float* lc    = (const float*)d_in[0];
  const float* p     = (const float*)d_in[1];
  const float* other = (const float*)d_in[2];
  const float* Wi    = (const float*)d_in[3];
  const float* bi    = (const float*)d_in[4];
  const float* Wr    = (const float*)d_in[5];
  const float* br    = (const float*)d_in[6];
  const float* Wo    = (const float*)d_in[7];
  const float* bo    = (const float*)d_in[8];
  float* out = (float*)d_out;

  char* wsb = (char*)d_ws;
  short* WtB      = (short*)wsb;
  short* featImg  = (short*)(wsb + WTB_BYTES);
  float* cell_sys = (float*)(wsb + WTB_BYTES + FEAT_BYTES);

  k_prep<<<798, 256, 0, stream>>>(lc, p, other, Wi, Wr, Wo, WtB, featImg, cell_sys);
  k_heavyR6<<<256, 1024, 0, stream>>>(featImg, WtB, lc, br, cell_sys);
  k_post<<<16, 512, 0, stream>>>(featImg, WtB, bi, bo, p, cell_sys, out);
}

// Round 2
// 248.950 us; speedup vs baseline: 1.0671x; 1.0671x over previous
//
#include <hip/hip_runtime.h>

// MassConservingLSTMCell — round 7: privatized accumulation (no atomic contention).
// R6 post-mortem: occupancy fix worked (42%) but 32 ug-blocks/Mb atomically
// accumulating the same cell_sys lines from different XCDs write-amplified 5x
// (WRITE_SIZE 33->164 MB) and ate the gain. R7: each block plain-stores its
// [128x256] tile to partial[ug] (32 copies, 32 MB ws); k_post fuses the 32-way
// reduce (into LDS) with the gate GEMMs and is re-gridded 16 -> 64 blocks
// (16 rows each) for 4x CU coverage. cell_sys eliminated. rsum padded to 12
// floats (16B-aligned rows, 2-way conflicts only). Falls back to single-copy
// atomic path if ws_size < 72 MB.
//
// B=1024, U=256, F=31, D=288 (9 k-chunks of 32).

#define EPS_L1 1e-7f

constexpr int BB  = 1024;
constexpr int U   = 256;
constexpr int F   = 31;
constexpr int D   = 1 + U + F;      // 288
constexpr int NBV = BB * U;         // 262144
constexpr int NCH = D / 32;         // 9
constexpr int UIMGB = NCH * 16384;  // 147456 B per u-slice B-image
constexpr size_t WTB_BYTES  = (size_t)258 * UIMGB;
constexpr size_t FEAT_BYTES = (size_t)BB * D * 2;
constexpr size_t PART_BYTES = (size_t)32 * BB * U * 4;   // 32 copies x 1 MB
constexpr size_t NEED_PRIV  = WTB_BYTES + FEAT_BYTES + PART_BYTES;
constexpr int PITCH = 260;

typedef float f32x4 __attribute__((ext_vector_type(4)));
typedef short bf16x8 __attribute__((ext_vector_type(8)));

__device__ __forceinline__ unsigned f2bf(float x) {
  union { float f; unsigned u; } v; v.f = x;
  unsigned r = v.u + 0x7FFFu + ((v.u >> 16) & 1u);
  return r >> 16;
}

#define GLDS16(gp, lp)                                                        \
  __builtin_amdgcn_global_load_lds(                                          \
      (const __attribute__((address_space(1))) void*)(gp),                   \
      (__attribute__((address_space(3))) void*)(lp), 16, 0, 0)

#define MFMA16(a, b, c) __builtin_amdgcn_mfma_f32_16x16x32_bf16((a), (b), (c), 0, 0, 0)

// ---------------------------------------------------------------- k_prep
__global__ __launch_bounds__(256) void k_prep(
    const float* __restrict__ lc, const float* __restrict__ p,
    const float* __restrict__ other,
    const float* __restrict__ Wi, const float* __restrict__ Wr,
    const float* __restrict__ Wo,
    short* __restrict__ WtB, short* __restrict__ featImg,
    float* __restrict__ partial) {
  __shared__ short lds[2][32 * PITCH];
  __shared__ float inv_s[64];
  const int bid = blockIdx.x, t = threadIdx.x;

  if (bid < 774) {
    // ---- weight transform: u-slice bid/3, chunks [3*(bid%3), +3)
    const int u = bid / 3, part = bid % 3;
    const float* src; long ld;
    if (u < 256)       { src = Wr + (size_t)u * 256; ld = 65536; }
    else if (u == 256) { src = Wi; ld = 256; }
    else               { src = Wo; ld = 256; }
    short* dst = WtB + (size_t)u * 73728;
    const int lane = t & 63, wave = t >> 6;
    const int g = lane >> 4, l15 = lane & 15;

#pragma unroll
    for (int cc = 0; cc < 3; ++cc) {
      const int c = part * 3 + cc;
      short* buf = lds[cc & 1];
      // phase 1: coalesced reads (1KB per wave-instruction)
#pragma unroll
      for (int i = 0; i < 8; ++i) {
        const int f = i * 256 + t;
        const int row = f >> 6, col4 = f & 63;
        const float4 v = *(const float4*)(src + (size_t)(c * 32 + row) * ld + col4 * 4);
        const unsigned lo = f2bf(v.x) | (f2bf(v.y) << 16);
        const unsigned hi = f2bf(v.z) | (f2bf(v.w) << 16);
        unsigned* wp = (unsigned*)&buf[row * PITCH + col4 * 4];
        wp[0] = lo; wp[1] = hi;
      }
      __syncthreads();
      // phase 2: fragment gather, 1KB-contiguous stores
#pragma unroll
      for (int i = 0; i < 4; ++i) {
        const int n0 = wave * 4 + i;
        bf16x8 h;
#pragma unroll
        for (int j = 0; j < 8; ++j)
          h[j] = buf[(g * 8 + j) * PITCH + n0 * 16 + l15];
        *(bf16x8*)(dst + (size_t)(c * 16 + n0) * 512 + lane * 8) = h;
      }
      __syncthreads();
    }
  } else if (bid < 790) {
    // ---- features -> A fragment image (64-row block mb)
    const int mb = bid - 774;
    const int b0 = mb * 64;
    const int row = t >> 2, q = t & 3;
    const float4* lp = (const float4*)(lc + (size_t)(b0 + row) * 256 + q * 64);
    float s = 0.f;
#pragma unroll
    for (int j = 0; j < 16; ++j) {
      const float4 v = lp[j];
      s += fabsf(v.x) + fabsf(v.y) + fabsf(v.z) + fabsf(v.w);
    }
    s += __shfl_xor(s, 1, 64);
    s += __shfl_xor(s, 2, 64);
    if (q == 0) inv_s[row] = 1.f / (s + EPS_L1);
    __syncthreads();
#pragma unroll
    for (int i = 0; i < 9; ++i) {
      const int idx = i * 256 + t;
      const int reg = idx >> 6, l = idx & 63;
      const int c = reg >> 2, mt = reg & 3;
      const int lrow = mt * 16 + (l & 15);
      const int grow = b0 + lrow;
      const int k0 = c * 32 + (l >> 4) * 8;
      bf16x8 h;
#pragma unroll
      for (int j = 0; j < 8; ++j) {
        const int k = k0 + j;
        float v;
        if (k == 0) v = p[grow];
        else if (k <= 256) v = lc[(size_t)grow * 256 + (k - 1)] * inv_s[lrow];
        else v = other[(size_t)grow * 31 + (k - 257)];
        h[j] = (short)f2bf(v);
      }
      *(bf16x8*)(featImg + (size_t)mb * 18432 + (size_t)reg * 512 + l * 8) = h;
    }
  } else {
    // ---- zero partial[0] (1 MB) — needed only by the atomic fallback path;
    //      harmless in the privatized path (fully overwritten by stores).
    float4* cs4 = (float4*)partial;
    const int base = (bid - 790) * 8192 + t;
    const float4 z = {0.f, 0.f, 0.f, 0.f};
#pragma unroll
    for (int k2 = 0; k2 < 32; ++k2) cs4[base + k2 * 256] = z;
  }
}

// ---------------------------------------------------------------- k_heavyR7
// 256 blocks (8 Mb x 32 ug), 1024 thr, 16 waves = 2 rh x 8 cq,
// wave tile 4mt x 2nt, 4 waves/SIMD. PRIV: plain stores to partial[ug];
// fallback: atomicAdd into partial[0].
template <bool PRIV>
__global__ __launch_bounds__(1024, 4) void k_heavyR7(
    const short* __restrict__ featImg, const short* __restrict__ WtB,
    const float* __restrict__ lc, const float* __restrict__ br,
    float* __restrict__ partial) {
  __shared__ short aT[36864];          // 73728 B: [rh][c][mt][1KB]
  __shared__ float rsum[2][128][12];   // padded: 48B rows (16B-aligned, 2-way)
  __shared__ float lcs[2][128];

  const int t = threadIdx.x, lane = t & 63, wave = t >> 6;
  const int cq = wave & 7, rh = wave >> 3;
  const int quad = lane >> 4, l15 = lane & 15;
  const int bid = blockIdx.x;
  const int Mb = bid >> 5, ug = bid & 31;   // ug%8 = XCD pin
  const int b0 = Mb * 128, u0 = ug * 8;

  // stage A (two 64-row images, linear; wave-uniform guard on tail chunk)
  {
    const char* gA = (const char*)featImg + (size_t)Mb * 73728;
    char* lA = (char*)aT;
#pragma unroll
    for (int i = 0; i < 5; ++i) {
      const int off = i * 16384 + t * 16;
      if (off < 73728) GLDS16(gA + off, lA + off);
    }
  }

  const char* aB = (const char*)aT + rh * 36864 + lane * 16;   // + c*4096 + m*1024
  const char* bB = (const char*)WtB + (size_t)u0 * UIMGB + cq * 2048 + lane * 16;

  f32x4 acc[4][2], outa[4][2];
#pragma unroll
  for (int m = 0; m < 4; ++m)
#pragma unroll
    for (int n = 0; n < 2; ++n)
#pragma unroll
      for (int r = 0; r < 4; ++r) { acc[m][n][r] = 0.f; outa[m][n][r] = 0.f; }

  bf16x8 afr[2][4], bfr[2][2];

  // B c=0 prefetch (before barrier; barrier drains it harmlessly)
#pragma unroll
  for (int n = 0; n < 2; ++n) bfr[0][n] = *(const bf16x8*)(bB + n * 1024);

  __syncthreads();   // A resident

#pragma unroll
  for (int m = 0; m < 4; ++m) afr[0][m] = *(const bf16x8*)(aB + m * 1024);

  for (int uu = 0; uu < 8; ++uu) {
    const int u = u0 + uu;
    float bv[2];

#pragma unroll
    for (int c = 0; c < 9; ++c) {
      if (c == 0) {
#pragma unroll
        for (int n = 0; n < 2; ++n)
          bv[n] = br[(size_t)u * 256 + cq * 32 + n * 16 + l15];
        if (t < 128) lcs[uu & 1][t] = lc[(size_t)(b0 + t) * 256 + u];
      }
      // dist-1 prefetch of c+1 (A from LDS, B from global/L2)
      if (c < 8) {
#pragma unroll
        for (int n = 0; n < 2; ++n)
          bfr[(c + 1) & 1][n] = *(const bf16x8*)(bB + (c + 1) * 16384 + n * 1024);
#pragma unroll
        for (int m = 0; m < 4; ++m)
          afr[(c + 1) & 1][m] = *(const bf16x8*)(aB + (c + 1) * 4096 + m * 1024);
      }
#pragma unroll
      for (int m = 0; m < 4; ++m)
#pragma unroll
        for (int n = 0; n < 2; ++n)
          acc[m][n] = MFMA16(afr[c & 1][m], bfr[c & 1][n], acc[m][n]);
    }
    bB += UIMGB;

    // next-u c=0 prefetch issued early; latency hides under the epilogue.
    // (Last u reads the u0+8 image — always inside WtB's 258 slices; unused.)
#pragma unroll
    for (int n = 0; n < 2; ++n) bfr[0][n] = *(const bf16x8*)(bB + n * 1024);
#pragma unroll
    for (int m = 0; m < 4; ++m) afr[0][m] = *(const bf16x8*)(aB + m * 1024);

    // ---- epilogue for u: bias+relu (into acc), cross-wave rownorm, accumulate
    const int ub = uu & 1;
    float sm[4][4];
#pragma unroll
    for (int m = 0; m < 4; ++m)
#pragma unroll
      for (int r = 0; r < 4; ++r) {
        float sv = 0.f;
#pragma unroll
        for (int n = 0; n < 2; ++n) {
          const float rv = fmaxf(acc[m][n][r] + bv[n], 0.f);
          acc[m][n][r] = rv;
          sv += rv;
        }
        sm[m][r] = sv;
      }
#pragma unroll
    for (int msk = 1; msk < 16; msk <<= 1)
#pragma unroll
      for (int m = 0; m < 4; ++m)
#pragma unroll
        for (int r = 0; r < 4; ++r)
          sm[m][r] += __shfl_xor(sm[m][r], msk, 64);
    if (l15 == 0) {
#pragma unroll
      for (int m = 0; m < 4; ++m)
#pragma unroll
        for (int r = 0; r < 4; ++r)
          rsum[ub][rh * 64 + m * 16 + quad * 4 + r][cq] = sm[m][r];
    }
    __syncthreads();
#pragma unroll
    for (int m = 0; m < 4; ++m)
#pragma unroll
      for (int r = 0; r < 4; ++r) {
        const int row = rh * 64 + m * 16 + quad * 4 + r;
        const float4 ra = *(const float4*)&rsum[ub][row][0];
        const float4 rb = *(const float4*)&rsum[ub][row][4];
        const float tot = ((ra.x + ra.y) + (ra.z + ra.w)) +
                          ((rb.x + rb.y) + (rb.z + rb.w));
        const float alpha = lcs[ub][row] * __builtin_amdgcn_rcpf(tot);
#pragma unroll
        for (int n = 0; n < 2; ++n) {
          outa[m][n][r] = fmaf(alpha, acc[m][n][r], outa[m][n][r]);
          acc[m][n][r] = 0.f;
        }
      }
  }

  const size_t pb = PRIV ? ((size_t)ug << 18) : 0;   // ug * 262144 floats
#pragma unroll
  for (int m = 0; m < 4; ++m)
#pragma unroll
    for (int r = 0; r < 4; ++r) {
      const int grow = b0 + rh * 64 + m * 16 + quad * 4 + r;
      const size_t rb = pb + (size_t)grow * 256 + cq * 32 + l15;
      if (PRIV) {
        partial[rb]      = outa[m][0][r];
        partial[rb + 16] = outa[m][1][r];
      } else {
        atomicAdd(&partial[rb],      outa[m][0][r]);
        atomicAdd(&partial[rb + 16], outa[m][1][r]);
      }
    }
}

// ---------------------------------------------------------------- k_postR7
// 64 blocks x 512 thr: 16 rows each. Fused: reduce npart partial copies into
// LDS, then gates MFMA (ig,og in regs) + final combine. 4x the CU coverage of
// the old 16-block k_post.
__global__ __launch_bounds__(512, 2) void k_postR7(
    const short* __restrict__ featImg, const short* __restrict__ WtB,
    const float* __restrict__ bi, const float* __restrict__ bo,
    const float* __restrict__ p, const float* __restrict__ partial, int npart,
    float* __restrict__ dout) {
  __shared__ short aT9[9 * 512];       // 9 KB: A fragments (c=0..8) for 16 rows
  __shared__ float cs[16 * 256];       // 16 KB: reduced cell_sys tile
  __shared__ float rsum[16][12];
  __shared__ float ps[16];

  const int t = threadIdx.x, lane = t & 63, cg = t >> 6;
  const int quad = lane >> 4, l15 = lane & 15;
  const int mb16 = blockIdx.x, b0 = mb16 * 16;
  const int mb = mb16 >> 2, mt = mb16 & 3;

  // stage A fragments: regs (c*4 + mt), c = 0..8  -> aT9[c*1024B]
  {
    const char* gsrc = (const char*)featImg + (size_t)mb * 36864 + mt * 1024;
    char* ldst = (char*)aT9;
    GLDS16(gsrc + (size_t)(t >> 6) * 4096 + (t & 63) * 16, ldst + t * 16);
    if (t < 64)
      GLDS16(gsrc + (size_t)8 * 4096 + t * 16, ldst + 8192 + t * 16);
  }
  if (t < 16) ps[t] = p[b0 + t];

  // reduce npart partial copies for rows [b0, b0+16) into cs
  {
    const float* pbase = partial + (size_t)b0 * 256;
    f32x4 s0 = {0.f, 0.f, 0.f, 0.f}, s1 = {0.f, 0.f, 0.f, 0.f};
#pragma unroll 4
    for (int ug = 0; ug < npart; ++ug) {
      const f32x4* pp = (const f32x4*)(pbase + (size_t)ug * 262144);
      s0 += pp[t];
      s1 += pp[512 + t];
    }
    ((f32x4*)cs)[t] = s0;
    ((f32x4*)cs)[512 + t] = s1;
  }

  f32x4 acc[2];
#pragma unroll
  for (int n = 0; n < 2; ++n)
#pragma unroll
    for (int r = 0; r < 4; ++r) acc[n][r] = 0.f;

  const char* bptr = (const char*)WtB + (size_t)256 * UIMGB + cg * 2048 + lane * 16;
  bf16x8 cb0 = *(const bf16x8*)(bptr);
  bf16x8 cb1 = *(const bf16x8*)(bptr + 1024);
  bf16x8 nb0 = *(const bf16x8*)(bptr + 16384);
  bf16x8 nb1 = *(const bf16x8*)(bptr + 16384 + 1024);
  bptr += 32768;

  __syncthreads();   // A fragments + cs resident

  float ig0[4], ig1[4], og0[4], og1[4];

#pragma unroll
  for (int g = 0; g < 2; ++g) {
    const float* bias = (g == 0) ? bi : bo;
    const float bv0 = bias[cg * 32 + l15];
    const float bv1 = bias[cg * 32 + 16 + l15];
#pragma unroll
    for (int c = 0; c < 9; ++c) {
      const bf16x8 pb0 = *(const bf16x8*)(bptr);
      const bf16x8 pb1 = *(const bf16x8*)(bptr + 1024);
      bptr += 16384;
      const bf16x8 a0 = *(const bf16x8*)((const char*)aT9 + c * 1024 + lane * 16);
      acc[0] = MFMA16(a0, cb0, acc[0]);
      acc[1] = MFMA16(a0, cb1, acc[1]);
      cb0 = nb0; cb1 = nb1; nb0 = pb0; nb1 = pb1;
    }

#pragma unroll
    for (int r = 0; r < 4; ++r) {
      const float v0 = 1.f / (1.f + __expf(-(acc[0][r] + bv0)));
      const float v1 = 1.f / (1.f + __expf(-(acc[1][r] + bv1)));
      if (g == 0) { ig0[r] = v0; ig1[r] = v1; }
      else        { og0[r] = v0; og1[r] = v1; }
      acc[0][r] = 0.f;
      acc[1][r] = 0.f;
    }

    if (g == 0) {
      float sm[4];
#pragma unroll
      for (int r = 0; r < 4; ++r) sm[r] = ig0[r] + ig1[r];
#pragma unroll
      for (int msk = 1; msk < 16; msk <<= 1)
#pragma unroll
        for (int r = 0; r < 4; ++r)
          sm[r] += __shfl_xor(sm[r], msk, 64);
      if (l15 == 0) {
#pragma unroll
        for (int r = 0; r < 4; ++r)
          rsum[quad * 4 + r][cg] = sm[r];
      }
      __syncthreads();
#pragma unroll
      for (int r = 0; r < 4; ++r) {
        const int row = quad * 4 + r;
        const float4 ra = *(const float4*)&rsum[row][0];
        const float4 rb = *(const float4*)&rsum[row][4];
        const float inv = 1.f / (((ra.x + ra.y) + (ra.z + ra.w)) +
                                 ((rb.x + rb.y) + (rb.z + rb.w)));
        ig0[r] *= inv;
        ig1[r] *= inv;
      }
    }
  }

#pragma unroll
  for (int r = 0; r < 4; ++r) {
    const int row = quad * 4 + r;
    const float pr = ps[row];
    const int ci = row * 256 + cg * 32 + l15;
    const size_t base = (size_t)(b0 + row) * 256 + cg * 32 + l15;
    {
      const float cand = fmaf(ig0[r], pr, cs[ci]);
      dout[base] = (1.f - og0[r]) * cand;
      dout[NBV + base] = og0[r] * cand;
    }
    {
      const float cand = fmaf(ig1[r], pr, cs[ci + 16]);
      dout[base + 16] = (1.f - og1[r]) * cand;
      dout[NBV + base + 16] = og1[r] * cand;
    }
  }
}

// ---------------------------------------------------------------- launch
extern "C" void kernel_launch(void* const* d_in, const int* in_sizes, int n_in,
                              void* d_out, int out_size, void* d_ws, size_t ws_size,
                              hipStream_t stream) {
  const float* lc    = (const float*)d_in[0];
  const float* p     = (const float*)d_in[1];
  const float* other = (const float*)d_in[2];
  const float* Wi    = (const float*)d_in[3];
  const float* bi    = (const float*)d_in[4];
  const float* Wr    = (const float*)d_in[5];
  const float* br    = (const float*)d_in[6];
  const float* Wo    = (const float*)d_in[7];
  const float* bo    = (const float*)d_in[8];
  float* out = (float*)d_out;

  char* wsb = (char*)d_ws;
  short* WtB      = (short*)wsb;
  short* featImg  = (short*)(wsb + WTB_BYTES);
  float* partial  = (float*)(wsb + WTB_BYTES + FEAT_BYTES);
  const bool priv = (ws_size >= NEED_PRIV);

  k_prep<<<798, 256, 0, stream>>>(lc, p, other, Wi, Wr, Wo, WtB, featImg, partial);
  if (priv)
    k_heavyR7<true><<<256, 1024, 0, stream>>>(featImg, WtB, lc, br, partial);
  else
    k_heavyR7<false><<<256, 1024, 0, stream>>>(featImg, WtB, lc, br, partial);
  k_postR7<<<64, 512, 0, stream>>>(featImg, WtB, bi, bo, p, partial,
                                   priv ? 32 : 1, out);
}

// Round 3
// 216.805 us; speedup vs baseline: 1.2254x; 1.1483x over previous
//
#include <hip/hip_runtime.h>

// MassConservingLSTMCell — round 8: revert k_heavy to verified R5 structure
// (78.6 us, atomic accumulation that empirically does NOT write-amplify at the
// 8-wave/512-thr shape), plus:
//  - k_heavy: hoist lc gather out of the u-loop (contiguous 32B/row once,
//    lcs[8][128]) — kills ~14 MB of stride-1KB gather overfetch.
//  - k_prep: weight transform rewritten as 2322 single-chunk blocks with
//    k-pair-packed LDS staging (tw[256][17] u32, odd pitch => <=2-way bank
//    conflicts); phase 2 is 16x ds_read_b32 + 16B stores (was 32x ds_read_u16
//    per chunk); block LDS 66.8 KB -> 17.7 KB (2 -> 8 blocks/CU).
//    WtB output is bit-identical to previous rounds (same f2bf, same layout).
//  - k_post: 64-block fused version (from R7, verified), reads cell_sys.
//
// B=1024, U=256, F=31, D=288 (9 k-chunks of 32).

#define EPS_L1 1e-7f

constexpr int BB  = 1024;
constexpr int U   = 256;
constexpr int F   = 31;
constexpr int D   = 1 + U + F;      // 288
constexpr int NBV = BB * U;         // 262144
constexpr int NCH = D / 32;         // 9
constexpr int UIMGB = NCH * 16384;  // 147456 B per u-slice B-image
constexpr size_t WTB_BYTES  = (size_t)258 * UIMGB;
constexpr size_t FEAT_BYTES = (size_t)BB * D * 2;

typedef float f32x4 __attribute__((ext_vector_type(4)));
typedef short bf16x8 __attribute__((ext_vector_type(8)));

__device__ __forceinline__ unsigned f2bf(float x) {
  union { float f; unsigned u; } v; v.f = x;
  unsigned r = v.u + 0x7FFFu + ((v.u >> 16) & 1u);
  return r >> 16;
}

#define GLDS16(gp, lp)                                                        \
  __builtin_amdgcn_global_load_lds(                                          \
      (const __attribute__((address_space(1))) void*)(gp),                   \
      (__attribute__((address_space(3))) void*)(lp), 16, 0, 0)

#define MFMA16(a, b, c) __builtin_amdgcn_mfma_f32_16x16x32_bf16((a), (b), (c), 0, 0, 0)

// ---------------------------------------------------------------- k_prep
// grid 2346 x 256:
//   [0..2322)    weight transform, block = (u, c) single chunk
//   [2322..2338) features -> A fragment images (16 x 64-row)
//   [2338..2346) zero cell_sys (1 MB)
__global__ __launch_bounds__(256) void k_prep(
    const float* __restrict__ lc, const float* __restrict__ p,
    const float* __restrict__ other,
    const float* __restrict__ Wi, const float* __restrict__ Wr,
    const float* __restrict__ Wo,
    short* __restrict__ WtB, short* __restrict__ featImg,
    float* __restrict__ cell_sys) {
  __shared__ unsigned tw[256][17];   // [v][k-pair], odd pitch: <=2-way conflicts
  __shared__ float inv_s[64];
  const int bid = blockIdx.x, t = threadIdx.x;

  if (bid < 2322) {
    // ---- weight transform: one 32k x 256v chunk of u-slice (u = bid/9, c = bid%9)
    const int u = bid / 9, c = bid % 9;
    const float* src; long ld;
    if (u < 256)       { src = Wr + (size_t)u * 256; ld = 65536; }
    else if (u == 256) { src = Wi; ld = 256; }
    else               { src = Wo; ld = 256; }

    // phase 1: coalesced float4 loads of two k-rows, pack k-pairs into u32,
    // transposed stage tw[v][kp]
    const int kp = t >> 4, f = t & 15;           // kp in [0,16), f in [0,16)
    const float* r0 = src + (size_t)(c * 32 + 2 * kp) * ld;
    const float* r1 = r0 + ld;
#pragma unroll
    for (int i = 0; i < 4; ++i) {
      const int v0 = f * 4 + i * 64;
      const float4 a = *(const float4*)(r0 + v0);
      const float4 b = *(const float4*)(r1 + v0);
      tw[v0 + 0][kp] = f2bf(a.x) | (f2bf(b.x) << 16);
      tw[v0 + 1][kp] = f2bf(a.y) | (f2bf(b.y) << 16);
      tw[v0 + 2][kp] = f2bf(a.z) | (f2bf(b.z) << 16);
      tw[v0 + 3][kp] = f2bf(a.w) | (f2bf(b.w) << 16);
    }
    __syncthreads();

    // phase 2: fragment gather — per fragment 4x ds_read_b32 (k-run is
    // contiguous in tw rows) + one 16B store. Layout identical to old WtB.
    const int lane = t & 63, wave = t >> 6;
    const int g = lane >> 4, l15 = lane & 15;
    short* dst = WtB + (size_t)u * 73728 + (size_t)c * 16 * 512;
#pragma unroll
    for (int ii = 0; ii < 4; ++ii) {
      const int n0 = wave * 4 + ii;
      const int row = n0 * 16 + l15;
      union { unsigned u4[4]; bf16x8 h; } cv;
#pragma unroll
      for (int j = 0; j < 4; ++j) cv.u4[j] = tw[row][g * 4 + j];
      *(bf16x8*)(dst + (size_t)n0 * 512 + lane * 8) = cv.h;
    }
  } else if (bid < 2338) {
    // ---- features -> A fragment image (64-row block mb)
    const int mb = bid - 2322;
    const int b0 = mb * 64;
    const int row = t >> 2, q = t & 3;
    const float4* lp = (const float4*)(lc + (size_t)(b0 + row) * 256 + q * 64);
    float s = 0.f;
#pragma unroll
    for (int j = 0; j < 16; ++j) {
      const float4 v = lp[j];
      s += fabsf(v.x) + fabsf(v.y) + fabsf(v.z) + fabsf(v.w);
    }
    s += __shfl_xor(s, 1, 64);
    s += __shfl_xor(s, 2, 64);
    if (q == 0) inv_s[row] = 1.f / (s + EPS_L1);
    __syncthreads();
#pragma unroll
    for (int i = 0; i < 9; ++i) {
      const int idx = i * 256 + t;
      const int reg = idx >> 6, l = idx & 63;
      const int c = reg >> 2, mt = reg & 3;
      const int lrow = mt * 16 + (l & 15);
      const int grow = b0 + lrow;
      const int k0 = c * 32 + (l >> 4) * 8;
      bf16x8 h;
#pragma unroll
      for (int j = 0; j < 8; ++j) {
        const int k = k0 + j;
        float v;
        if (k == 0) v = p[grow];
        else if (k <= 256) v = lc[(size_t)grow * 256 + (k - 1)] * inv_s[lrow];
        else v = other[(size_t)grow * 31 + (k - 257)];
        h[j] = (short)f2bf(v);
      }
      *(bf16x8*)(featImg + (size_t)mb * 18432 + (size_t)reg * 512 + l * 8) = h;
    }
  } else {
    // ---- zero cell_sys (1 MB)
    float4* cs4 = (float4*)cell_sys;
    const int base = (bid - 2338) * 8192 + t;
    const float4 z = {0.f, 0.f, 0.f, 0.f};
#pragma unroll
    for (int k2 = 0; k2 < 32; ++k2) cs4[base + k2 * 256] = z;
  }
}

// ---------------------------------------------------------------- k_heavyR8
// R5 structure verbatim (256 blocks = 8 Mb x 32 ug, 512 thr, 8 waves = 2rh x 4cq,
// wave tile 4mt x 4nt, dist-2 B prefetch, atomic accumulate) + lcs hoisted:
// lc[b][u0..u0+8) loaded once, contiguous, before the main loop.
__global__ __launch_bounds__(512, 2) void k_heavyR8(
    const short* __restrict__ featImg, const short* __restrict__ WtB,
    const float* __restrict__ lc, const float* __restrict__ br,
    float* __restrict__ cell_sys) {
  __shared__ short aT[36864];          // 73728 B: [rh][c][mt][1KB]
  __shared__ float rsum[2][128][4];    // [par][row][cq]
  __shared__ float lcs[8][128];        // [uu][row] — filled once pre-loop

  const int t = threadIdx.x, lane = t & 63, wave = t >> 6;
  const int cq = wave & 3, rh = wave >> 2;
  const int quad = lane >> 4, l15 = lane & 15;
  const int bid = blockIdx.x;
  const int Mb = bid >> 5, ug = bid & 31;   // ug%8 = XCD pin
  const int b0 = Mb * 128, u0 = ug * 8;

  // stage A (two 64-row images, linear)
  {
    const char* gA = (const char*)featImg + (size_t)Mb * 73728;
    char* lA = (char*)aT;
#pragma unroll
    for (int i = 0; i < 9; ++i)
      GLDS16(gA + i * 8192 + t * 16, lA + i * 8192 + t * 16);
  }

  // lc hoist: 8 contiguous floats per row (two float4s), once.
  if (t < 128) {
    const float* lp = lc + (size_t)(b0 + t) * 256 + u0;
    const float4 v0 = *(const float4*)(lp);
    const float4 v1 = *(const float4*)(lp + 4);
    lcs[0][t] = v0.x; lcs[1][t] = v0.y; lcs[2][t] = v0.z; lcs[3][t] = v0.w;
    lcs[4][t] = v1.x; lcs[5][t] = v1.y; lcs[6][t] = v1.z; lcs[7][t] = v1.w;
  }

  const char* aB = (const char*)aT + rh * 36864 + lane * 16;   // + c*4096 + m*1024
  const char* bB = (const char*)WtB + (size_t)u0 * UIMGB + cq * 4096 + lane * 16;

  f32x4 acc[4][4], outa[4][4];
#pragma unroll
  for (int m = 0; m < 4; ++m)
#pragma unroll
    for (int n = 0; n < 4; ++n)
#pragma unroll
      for (int r = 0; r < 4; ++r) { acc[m][n][r] = 0.f; outa[m][n][r] = 0.f; }

  // B distance-2 prefetch: 3-slot static rotation
  bf16x8 bfr[3][4];
#pragma unroll
  for (int n = 0; n < 4; ++n) bfr[0][n] = *(const bf16x8*)(bB + n * 1024);
#pragma unroll
  for (int n = 0; n < 4; ++n) bfr[1][n] = *(const bf16x8*)(bB + 16384 + n * 1024);

  __syncthreads();   // A + lcs resident (drains GLDS + B prefetch harmlessly)

  // A distance-1 prefetch: 2-slot rotation; afr[0] = A[0]
  bf16x8 afr[2][4];
#pragma unroll
  for (int m = 0; m < 4; ++m) afr[0][m] = *(const bf16x8*)(aB + m * 1024);

  for (int uu = 0; uu < 8; ++uu) {
    const int u = u0 + uu;
    float bv[4];

#pragma unroll
    for (int c = 0; c < 9; ++c) {
      if (c == 0) {
#pragma unroll
        for (int n = 0; n < 4; ++n)
          bv[n] = br[(size_t)u * 256 + cq * 64 + n * 16 + l15];
      }
      // B prefetch c+2 (flat; crosses into u+1's image at c>=7)
#pragma unroll
      for (int n = 0; n < 4; ++n)
        bfr[(c + 2) % 3][n] = *(const bf16x8*)(bB + (c + 2) * 16384 + n * 1024);
      // A prefetch c+1 (skip at c==8; epilogue reloads A[0])
      if (c < 8) {
#pragma unroll
        for (int m = 0; m < 4; ++m)
          afr[(c + 1) & 1][m] = *(const bf16x8*)(aB + (c + 1) * 4096 + m * 1024);
      }
#pragma unroll
      for (int m = 0; m < 4; ++m)
#pragma unroll
        for (int n = 0; n < 4; ++n)
          acc[m][n] = MFMA16(afr[c & 1][m], bfr[c % 3][n], acc[m][n]);
    }
    bB += UIMGB;

    // issue next-u A[0] reload early (content static; hidden under epilogue)
#pragma unroll
    for (int m = 0; m < 4; ++m) afr[0][m] = *(const bf16x8*)(aB + m * 1024);

    // ---- epilogue for u: bias+relu (into acc), cross-wave rownorm, accumulate
    const int ub = uu & 1;
    float sm[4][4];
#pragma unroll
    for (int m = 0; m < 4; ++m)
#pragma unroll
      for (int r = 0; r < 4; ++r) {
        float sv = 0.f;
#pragma unroll
        for (int n = 0; n < 4; ++n) {
          const float rv = fmaxf(acc[m][n][r] + bv[n], 0.f);
          acc[m][n][r] = rv;
          sv += rv;
        }
        sm[m][r] = sv;
      }
#pragma unroll
    for (int msk = 1; msk < 16; msk <<= 1)
#pragma unroll
      for (int m = 0; m < 4; ++m)
#pragma unroll
        for (int r = 0; r < 4; ++r)
          sm[m][r] += __shfl_xor(sm[m][r], msk, 64);
    if (l15 == 0) {
#pragma unroll
      for (int m = 0; m < 4; ++m)
#pragma unroll
        for (int r = 0; r < 4; ++r)
          rsum[ub][rh * 64 + m * 16 + quad * 4 + r][cq] = sm[m][r];
    }
    __syncthreads();
#pragma unroll
    for (int m = 0; m < 4; ++m)
#pragma unroll
      for (int r = 0; r < 4; ++r) {
        const int row = rh * 64 + m * 16 + quad * 4 + r;
        const float4 rv = *(const float4*)&rsum[ub][row][0];
        const float tot = (rv.x + rv.y) + (rv.z + rv.w);
        const float alpha = lcs[uu][row] * __builtin_amdgcn_rcpf(tot);
#pragma unroll
        for (int n = 0; n < 4; ++n) {
          outa[m][n][r] = fmaf(alpha, acc[m][n][r], outa[m][n][r]);
          acc[m][n][r] = 0.f;
        }
      }
  }

#pragma unroll
  for (int m = 0; m < 4; ++m)
#pragma unroll
    for (int r = 0; r < 4; ++r) {
      const int grow = b0 + rh * 64 + m * 16 + quad * 4 + r;
#pragma unroll
      for (int n = 0; n < 4; ++n)
        atomicAdd(&cell_sys[(size_t)grow * 256 + cq * 64 + n * 16 + l15],
                  outa[m][n][r]);
    }
}

// ---------------------------------------------------------------- k_postR8
// 64 blocks x 512 thr: 16 rows each. cell_sys tile -> LDS, gates MFMA
// (ig,og in regs) + final combine.
__global__ __launch_bounds__(512, 2) void k_postR8(
    const short* __restrict__ featImg, const short* __restrict__ WtB,
    const float* __restrict__ bi, const float* __restrict__ bo,
    const float* __restrict__ p, const float* __restrict__ cell_sys,
    float* __restrict__ dout) {
  __shared__ short aT9[9 * 512];       // 9 KB: A fragments (c=0..8) for 16 rows
  __shared__ float cs[16 * 256];       // 16 KB: cell_sys tile
  __shared__ float rsum[16][12];
  __shared__ float ps[16];

  const int t = threadIdx.x, lane = t & 63, cg = t >> 6;
  const int quad = lane >> 4, l15 = lane & 15;
  const int mb16 = blockIdx.x, b0 = mb16 * 16;
  const int mb = mb16 >> 2, mt = mb16 & 3;

  // stage A fragments: regs (c*4 + mt), c = 0..8  -> aT9[c*1024B]
  {
    const char* gsrc = (const char*)featImg + (size_t)mb * 36864 + mt * 1024;
    char* ldst = (char*)aT9;
    GLDS16(gsrc + (size_t)(t >> 6) * 4096 + (t & 63) * 16, ldst + t * 16);
    if (t < 64)
      GLDS16(gsrc + (size_t)8 * 4096 + t * 16, ldst + 8192 + t * 16);
  }
  if (t < 16) ps[t] = p[b0 + t];

  // copy cell_sys rows [b0, b0+16) into cs
  {
    const f32x4* pp = (const f32x4*)(cell_sys + (size_t)b0 * 256);
    ((f32x4*)cs)[t] = pp[t];
    ((f32x4*)cs)[512 + t] = pp[512 + t];
  }

  f32x4 acc[2];
#pragma unroll
  for (int n = 0; n < 2; ++n)
#pragma unroll
    for (int r = 0; r < 4; ++r) acc[n][r] = 0.f;

  const char* bptr = (const char*)WtB + (size_t)256 * UIMGB + cg * 2048 + lane * 16;
  bf16x8 cb0 = *(const bf16x8*)(bptr);
  bf16x8 cb1 = *(const bf16x8*)(bptr + 1024);
  bf16x8 nb0 = *(const bf16x8*)(bptr + 16384);
  bf16x8 nb1 = *(const bf16x8*)(bptr + 16384 + 1024);
  bptr += 32768;

  __syncthreads();   // A fragments + cs resident

  float ig0[4], ig1[4], og0[4], og1[4];

#pragma unroll
  for (int g = 0; g < 2; ++g) {
    const float* bias = (g == 0) ? bi : bo;
    const float bv0 = bias[cg * 32 + l15];
    const float bv1 = bias[cg * 32 + 16 + l15];
#pragma unroll
    for (int c = 0; c < 9; ++c) {
      const bf16x8 pb0 = *(const bf16x8*)(bptr);
      const bf16x8 pb1 = *(const bf16x8*)(bptr + 1024);
      bptr += 16384;
      const bf16x8 a0 = *(const bf16x8*)((const char*)aT9 + c * 1024 + lane * 16);
      acc[0] = MFMA16(a0, cb0, acc[0]);
      acc[1] = MFMA16(a0, cb1, acc[1]);
      cb0 = nb0; cb1 = nb1; nb0 = pb0; nb1 = pb1;
    }

#pragma unroll
    for (int r = 0; r < 4; ++r) {
      const float v0 = 1.f / (1.f + __expf(-(acc[0][r] + bv0)));
      const float v1 = 1.f / (1.f + __expf(-(acc[1][r] + bv1)));
      if (g == 0) { ig0[r] = v0; ig1[r] = v1; }
      else        { og0[r] = v0; og1[r] = v1; }
      acc[0][r] = 0.f;
      acc[1][r] = 0.f;
    }

    if (g == 0) {
      float sm[4];
#pragma unroll
      for (int r = 0; r < 4; ++r) sm[r] = ig0[r] + ig1[r];
#pragma unroll
      for (int msk = 1; msk < 16; msk <<= 1)
#pragma unroll
        for (int r = 0; r < 4; ++r)
          sm[r] += __shfl_xor(sm[r], msk, 64);
      if (l15 == 0) {
#pragma unroll
        for (int r = 0; r < 4; ++r)
          rsum[quad * 4 + r][cg] = sm[r];
      }
      __syncthreads();
#pragma unroll
      for (int r = 0; r < 4; ++r) {
        const int row = quad * 4 + r;
        const float4 ra = *(const float4*)&rsum[row][0];
        const float4 rb = *(const float4*)&rsum[row][4];
        const float inv = 1.f / (((ra.x + ra.y) + (ra.z + ra.w)) +
                                 ((rb.x + rb.y) + (rb.z + rb.w)));
        ig0[r] *= inv;
        ig1[r] *= inv;
      }
    }
  }

#pragma unroll
  for (int r = 0; r < 4; ++r) {
    const int row = quad * 4 + r;
    const float pr = ps[row];
    const int ci = row * 256 + cg * 32 + l15;
    const size_t base = (size_t)(b0 + row) * 256 + cg * 32 + l15;
    {
      const float cand = fmaf(ig0[r], pr, cs[ci]);
      dout[base] = (1.f - og0[r]) * cand;
      dout[NBV + base] = og0[r] * cand;
    }
    {
      const float cand = fmaf(ig1[r], pr, cs[ci + 16]);
      dout[base + 16] = (1.f - og1[r]) * cand;
      dout[NBV + base + 16] = og1[r] * cand;
    }
  }
}

// ---------------------------------------------------------------- launch
extern "C" void kernel_launch(void* const* d_in, const int* in_sizes, int n_in,
                              void* d_out, int out_size, void* d_ws, size_t ws_size,
                              hipStream_t stream) {
  const float* lc    = (const float*)d_in[0];
  const float* p     = (const float*)d_in[1];
  const float* other = (const float*)d_in[2];
  const float* Wi    = (const float*)d_in[3];
  const float* bi    = (const float*)d_in[4];
  const float* Wr    = (const float*)d_in[5];
  const float* br    = (const float*)d_in[6];
  const float* Wo    = (const float*)d_in[7];
  const float* bo    = (const float*)d_in[8];
  float* out = (float*)d_out;

  char* wsb = (char*)d_ws;
  short* WtB      = (short*)wsb;
  short* featImg  = (short*)(wsb + WTB_BYTES);
  float* cell_sys = (float*)(wsb + WTB_BYTES + FEAT_BYTES);

  k_prep<<<2346, 256, 0, stream>>>(lc, p, other, Wi, Wr, Wo, WtB, featImg, cell_sys);
  k_heavyR8<<<256, 512, 0, stream>>>(featImg, WtB, lc, br, cell_sys);
  k_postR8<<<64, 512, 0, stream>>>(featImg, WtB, bi, bo, p, cell_sys, out);
}

// Round 4
// 214.290 us; speedup vs baseline: 1.2398x; 1.0117x over previous
//
#include <hip/hip_runtime.h>

// MassConservingLSTMCell — round 9: k_heavy occupancy via grid split.
// R8 diagnosis: occupancy 20% because grid=256 = exactly 1 block/CU (VGPR and
// LDS would both allow more). R9: 512 blocks (16 Mb x 32 ug) x 512 thr,
// 64 rows/block (one featImg image, 36.9 KB LDS), wave tile 2mt x 4nt,
// dist-1 A/B prefetch, regs <=128 (launch_bounds(512,4)) -> 2 blocks/CU,
// 16 waves/CU. Atomic payload unchanged (WRITE_SIZE must stay 32 MB — that
// counter is the revert criterion). k_prep / k_postR8 unchanged from R8.
//
// B=1024, U=256, F=31, D=288 (9 k-chunks of 32).

#define EPS_L1 1e-7f

constexpr int BB  = 1024;
constexpr int U   = 256;
constexpr int F   = 31;
constexpr int D   = 1 + U + F;      // 288
constexpr int NBV = BB * U;         // 262144
constexpr int NCH = D / 32;         // 9
constexpr int UIMGB = NCH * 16384;  // 147456 B per u-slice B-image
constexpr size_t WTB_BYTES  = (size_t)258 * UIMGB;
constexpr size_t FEAT_BYTES = (size_t)BB * D * 2;

typedef float f32x4 __attribute__((ext_vector_type(4)));
typedef short bf16x8 __attribute__((ext_vector_type(8)));

__device__ __forceinline__ unsigned f2bf(float x) {
  union { float f; unsigned u; } v; v.f = x;
  unsigned r = v.u + 0x7FFFu + ((v.u >> 16) & 1u);
  return r >> 16;
}

#define GLDS16(gp, lp)                                                        \
  __builtin_amdgcn_global_load_lds(                                          \
      (const __attribute__((address_space(1))) void*)(gp),                   \
      (__attribute__((address_space(3))) void*)(lp), 16, 0, 0)

#define MFMA16(a, b, c) __builtin_amdgcn_mfma_f32_16x16x32_bf16((a), (b), (c), 0, 0, 0)

// ---------------------------------------------------------------- k_prep
// grid 2346 x 256:
//   [0..2322)    weight transform, block = (u, c) single chunk
//   [2322..2338) features -> A fragment images (16 x 64-row)
//   [2338..2346) zero cell_sys (1 MB)
__global__ __launch_bounds__(256) void k_prep(
    const float* __restrict__ lc, const float* __restrict__ p,
    const float* __restrict__ other,
    const float* __restrict__ Wi, const float* __restrict__ Wr,
    const float* __restrict__ Wo,
    short* __restrict__ WtB, short* __restrict__ featImg,
    float* __restrict__ cell_sys) {
  __shared__ unsigned tw[256][17];   // [v][k-pair], odd pitch: <=2-way conflicts
  __shared__ float inv_s[64];
  const int bid = blockIdx.x, t = threadIdx.x;

  if (bid < 2322) {
    // ---- weight transform: one 32k x 256v chunk of u-slice (u = bid/9, c = bid%9)
    const int u = bid / 9, c = bid % 9;
    const float* src; long ld;
    if (u < 256)       { src = Wr + (size_t)u * 256; ld = 65536; }
    else if (u == 256) { src = Wi; ld = 256; }
    else               { src = Wo; ld = 256; }

    // phase 1: coalesced float4 loads of two k-rows, pack k-pairs into u32,
    // transposed stage tw[v][kp]
    const int kp = t >> 4, f = t & 15;           // kp in [0,16), f in [0,16)
    const float* r0 = src + (size_t)(c * 32 + 2 * kp) * ld;
    const float* r1 = r0 + ld;
#pragma unroll
    for (int i = 0; i < 4; ++i) {
      const int v0 = f * 4 + i * 64;
      const float4 a = *(const float4*)(r0 + v0);
      const float4 b = *(const float4*)(r1 + v0);
      tw[v0 + 0][kp] = f2bf(a.x) | (f2bf(b.x) << 16);
      tw[v0 + 1][kp] = f2bf(a.y) | (f2bf(b.y) << 16);
      tw[v0 + 2][kp] = f2bf(a.z) | (f2bf(b.z) << 16);
      tw[v0 + 3][kp] = f2bf(a.w) | (f2bf(b.w) << 16);
    }
    __syncthreads();

    // phase 2: fragment gather — per fragment 4x ds_read_b32 (k-run is
    // contiguous in tw rows) + one 16B store. Layout identical to old WtB.
    const int lane = t & 63, wave = t >> 6;
    const int g = lane >> 4, l15 = lane & 15;
    short* dst = WtB + (size_t)u * 73728 + (size_t)c * 16 * 512;
#pragma unroll
    for (int ii = 0; ii < 4; ++ii) {
      const int n0 = wave * 4 + ii;
      const int row = n0 * 16 + l15;
      union { unsigned u4[4]; bf16x8 h; } cv;
#pragma unroll
      for (int j = 0; j < 4; ++j) cv.u4[j] = tw[row][g * 4 + j];
      *(bf16x8*)(dst + (size_t)n0 * 512 + lane * 8) = cv.h;
    }
  } else if (bid < 2338) {
    // ---- features -> A fragment image (64-row block mb)
    const int mb = bid - 2322;
    const int b0 = mb * 64;
    const int row = t >> 2, q = t & 3;
    const float4* lp = (const float4*)(lc + (size_t)(b0 + row) * 256 + q * 64);
    float s = 0.f;
#pragma unroll
    for (int j = 0; j < 16; ++j) {
      const float4 v = lp[j];
      s += fabsf(v.x) + fabsf(v.y) + fabsf(v.z) + fabsf(v.w);
    }
    s += __shfl_xor(s, 1, 64);
    s += __shfl_xor(s, 2, 64);
    if (q == 0) inv_s[row] = 1.f / (s + EPS_L1);
    __syncthreads();
#pragma unroll
    for (int i = 0; i < 9; ++i) {
      const int idx = i * 256 + t;
      const int reg = idx >> 6, l = idx & 63;
      const int c = reg >> 2, mt = reg & 3;
      const int lrow = mt * 16 + (l & 15);
      const int grow = b0 + lrow;
      const int k0 = c * 32 + (l >> 4) * 8;
      bf16x8 h;
#pragma unroll
      for (int j = 0; j < 8; ++j) {
        const int k = k0 + j;
        float v;
        if (k == 0) v = p[grow];
        else if (k <= 256) v = lc[(size_t)grow * 256 + (k - 1)] * inv_s[lrow];
        else v = other[(size_t)grow * 31 + (k - 257)];
        h[j] = (short)f2bf(v);
      }
      *(bf16x8*)(featImg + (size_t)mb * 18432 + (size_t)reg * 512 + l * 8) = h;
    }
  } else {
    // ---- zero cell_sys (1 MB)
    float4* cs4 = (float4*)cell_sys;
    const int base = (bid - 2338) * 8192 + t;
    const float4 z = {0.f, 0.f, 0.f, 0.f};
#pragma unroll
    for (int k2 = 0; k2 < 32; ++k2) cs4[base + k2 * 256] = z;
  }
}

// ---------------------------------------------------------------- k_heavyR9
// 512 blocks (16 Mb x 32 ug), 512 thr, 8 waves = 2 rh x 4 cq,
// wave tile 2mt x 4nt, dist-1 A/B prefetch, <=128 regs -> 2 blocks/CU.
__global__ __launch_bounds__(512, 4) void k_heavyR9(
    const short* __restrict__ featImg, const short* __restrict__ WtB,
    const float* __restrict__ lc, const float* __restrict__ br,
    float* __restrict__ cell_sys) {
  __shared__ short aT[18432];          // 36864 B: [c][mt][1KB], one 64-row image
  __shared__ float rsum[2][64][4];     // [par][row][cq]
  __shared__ float lcs[8][64];         // [uu][row]

  const int t = threadIdx.x, lane = t & 63, wave = t >> 6;
  const int cq = wave & 3, rh = wave >> 2;
  const int quad = lane >> 4, l15 = lane & 15;
  const int bid = blockIdx.x;
  const int Mb = bid >> 5, ug = bid & 31;   // bid%8 = ug%8 = XCD pin
  const int b0 = Mb * 64, u0 = ug * 8;

  // stage A (one 64-row image, linear; guard is wave-uniform: t<256)
  {
    const char* gA = (const char*)featImg + (size_t)Mb * 36864;
    char* lA = (char*)aT;
#pragma unroll
    for (int i = 0; i < 5; ++i) {
      const int off = i * 8192 + t * 16;
      if (off < 36864) GLDS16(gA + off, lA + off);
    }
  }

  // lc hoist: 8 contiguous floats per row, once.
  if (t < 64) {
    const float* lp = lc + (size_t)(b0 + t) * 256 + u0;
    const float4 v0 = *(const float4*)(lp);
    const float4 v1 = *(const float4*)(lp + 4);
    lcs[0][t] = v0.x; lcs[1][t] = v0.y; lcs[2][t] = v0.z; lcs[3][t] = v0.w;
    lcs[4][t] = v1.x; lcs[5][t] = v1.y; lcs[6][t] = v1.z; lcs[7][t] = v1.w;
  }

  // fragment base addresses:
  //   A frag (c, m): aT + rh*2048 + c*4096 + m*1024 + lane*16   (m = 0..1)
  //   B frag (c, n): WtB[u] + cq*4096 + c*16384 + n*1024 + lane*16
  const char* aB = (const char*)aT + rh * 2048 + lane * 16;
  const char* bB = (const char*)WtB + (size_t)u0 * UIMGB + cq * 4096 + lane * 16;

  f32x4 acc[2][4], outa[2][4];
#pragma unroll
  for (int m = 0; m < 2; ++m)
#pragma unroll
    for (int n = 0; n < 4; ++n)
#pragma unroll
      for (int r = 0; r < 4; ++r) { acc[m][n][r] = 0.f; outa[m][n][r] = 0.f; }

  bf16x8 afr[2][2], bfr[2][4];

  // B c=0 prefetch (pre-barrier; barrier drains it harmlessly)
#pragma unroll
  for (int n = 0; n < 4; ++n) bfr[0][n] = *(const bf16x8*)(bB + n * 1024);

  __syncthreads();   // A + lcs resident

#pragma unroll
  for (int m = 0; m < 2; ++m) afr[0][m] = *(const bf16x8*)(aB + m * 1024);

  for (int uu = 0; uu < 8; ++uu) {
    const int u = u0 + uu;
    float bv[4];

#pragma unroll
    for (int c = 0; c < 9; ++c) {
      if (c == 0) {
#pragma unroll
        for (int n = 0; n < 4; ++n)
          bv[n] = br[(size_t)u * 256 + cq * 64 + n * 16 + l15];
      }
      // dist-1 prefetch of c+1 (A from LDS, B from L2)
      if (c < 8) {
#pragma unroll
        for (int n = 0; n < 4; ++n)
          bfr[(c + 1) & 1][n] = *(const bf16x8*)(bB + (c + 1) * 16384 + n * 1024);
#pragma unroll
        for (int m = 0; m < 2; ++m)
          afr[(c + 1) & 1][m] = *(const bf16x8*)(aB + (c + 1) * 4096 + m * 1024);
      }
#pragma unroll
      for (int m = 0; m < 2; ++m)
#pragma unroll
        for (int n = 0; n < 4; ++n)
          acc[m][n] = MFMA16(afr[c & 1][m], bfr[c & 1][n], acc[m][n]);
    }
    bB += UIMGB;

    // next-u c=0 prefetch into slot 0; latency hides under the epilogue.
    // (Last u reads the u0+8 image — always inside WtB's 258 slices; unused.)
#pragma unroll
    for (int n = 0; n < 4; ++n) bfr[0][n] = *(const bf16x8*)(bB + n * 1024);
#pragma unroll
    for (int m = 0; m < 2; ++m) afr[0][m] = *(const bf16x8*)(aB + m * 1024);

    // ---- epilogue for u: bias+relu (into acc), cross-wave rownorm, accumulate
    const int ub = uu & 1;
    float sm[2][4];
#pragma unroll
    for (int m = 0; m < 2; ++m)
#pragma unroll
      for (int r = 0; r < 4; ++r) {
        float sv = 0.f;
#pragma unroll
        for (int n = 0; n < 4; ++n) {
          const float rv = fmaxf(acc[m][n][r] + bv[n], 0.f);
          acc[m][n][r] = rv;
          sv += rv;
        }
        sm[m][r] = sv;
      }
#pragma unroll
    for (int msk = 1; msk < 16; msk <<= 1)
#pragma unroll
      for (int m = 0; m < 2; ++m)
#pragma unroll
        for (int r = 0; r < 4; ++r)
          sm[m][r] += __shfl_xor(sm[m][r], msk, 64);
    if (l15 == 0) {
#pragma unroll
      for (int m = 0; m < 2; ++m)
#pragma unroll
        for (int r = 0; r < 4; ++r)
          rsum[ub][rh * 32 + m * 16 + quad * 4 + r][cq] = sm[m][r];
    }
    __syncthreads();
#pragma unroll
    for (int m = 0; m < 2; ++m)
#pragma unroll
      for (int r = 0; r < 4; ++r) {
        const int row = rh * 32 + m * 16 + quad * 4 + r;
        const float4 rv = *(const float4*)&rsum[ub][row][0];
        const float tot = (rv.x + rv.y) + (rv.z + rv.w);
        const float alpha = lcs[uu][row] * __builtin_amdgcn_rcpf(tot);
#pragma unroll
        for (int n = 0; n < 4; ++n) {
          outa[m][n][r] = fmaf(alpha, acc[m][n][r], outa[m][n][r]);
          acc[m][n][r] = 0.f;
        }
      }
  }

#pragma unroll
  for (int m = 0; m < 2; ++m)
#pragma unroll
    for (int r = 0; r < 4; ++r) {
      const int grow = b0 + rh * 32 + m * 16 + quad * 4 + r;
#pragma unroll
      for (int n = 0; n < 4; ++n)
        atomicAdd(&cell_sys[(size_t)grow * 256 + cq * 64 + n * 16 + l15],
                  outa[m][n][r]);
    }
}

// ---------------------------------------------------------------- k_postR8
// 64 blocks x 512 thr: 16 rows each. cell_sys tile -> LDS, gates MFMA
// (ig,og in regs) + final combine.
__global__ __launch_bounds__(512, 2) void k_postR8(
    const short* __restrict__ featImg, const short* __restrict__ WtB,
    const float* __restrict__ bi, const float* __restrict__ bo,
    const float* __restrict__ p, const float* __restrict__ cell_sys,
    float* __restrict__ dout) {
  __shared__ short aT9[9 * 512];       // 9 KB: A fragments (c=0..8) for 16 rows
  __shared__ float cs[16 * 256];       // 16 KB: cell_sys tile
  __shared__ float rsum[16][12];
  __shared__ float ps[16];

  const int t = threadIdx.x, lane = t & 63, cg = t >> 6;
  const int quad = lane >> 4, l15 = lane & 15;
  const int mb16 = blockIdx.x, b0 = mb16 * 16;
  const int mb = mb16 >> 2, mt = mb16 & 3;

  // stage A fragments: regs (c*4 + mt), c = 0..8  -> aT9[c*1024B]
  {
    const char* gsrc = (const char*)featImg + (size_t)mb * 36864 + mt * 1024;
    char* ldst = (char*)aT9;
    GLDS16(gsrc + (size_t)(t >> 6) * 4096 + (t & 63) * 16, ldst + t * 16);
    if (t < 64)
      GLDS16(gsrc + (size_t)8 * 4096 + t * 16, ldst + 8192 + t * 16);
  }
  if (t < 16) ps[t] = p[b0 + t];

  // copy cell_sys rows [b0, b0+16) into cs
  {
    const f32x4* pp = (const f32x4*)(cell_sys + (size_t)b0 * 256);
    ((f32x4*)cs)[t] = pp[t];
    ((f32x4*)cs)[512 + t] = pp[512 + t];
  }

  f32x4 acc[2];
#pragma unroll
  for (int n = 0; n < 2; ++n)
#pragma unroll
    for (int r = 0; r < 4; ++r) acc[n][r] = 0.f;

  const char* bptr = (const char*)WtB + (size_t)256 * UIMGB + cg * 2048 + lane * 16;
  bf16x8 cb0 = *(const bf16x8*)(bptr);
  bf16x8 cb1 = *(const bf16x8*)(bptr + 1024);
  bf16x8 nb0 = *(const bf16x8*)(bptr + 16384);
  bf16x8 nb1 = *(const bf16x8*)(bptr + 16384 + 1024);
  bptr += 32768;

  __syncthreads();   // A fragments + cs resident

  float ig0[4], ig1[4], og0[4], og1[4];

#pragma unroll
  for (int g = 0; g < 2; ++g) {
    const float* bias = (g == 0) ? bi : bo;
    const float bv0 = bias[cg * 32 + l15];
    const float bv1 = bias[cg * 32 + 16 + l15];
#pragma unroll
    for (int c = 0; c < 9; ++c) {
      const bf16x8 pb0 = *(const bf16x8*)(bptr);
      const bf16x8 pb1 = *(const bf16x8*)(bptr + 1024);
      bptr += 16384;
      const bf16x8 a0 = *(const bf16x8*)((const char*)aT9 + c * 1024 + lane * 16);
      acc[0] = MFMA16(a0, cb0, acc[0]);
      acc[1] = MFMA16(a0, cb1, acc[1]);
      cb0 = nb0; cb1 = nb1; nb0 = pb0; nb1 = pb1;
    }

#pragma unroll
    for (int r = 0; r < 4; ++r) {
      const float v0 = 1.f / (1.f + __expf(-(acc[0][r] + bv0)));
      const float v1 = 1.f / (1.f + __expf(-(acc[1][r] + bv1)));
      if (g == 0) { ig0[r] = v0; ig1[r] = v1; }
      else        { og0[r] = v0; og1[r] = v1; }
      acc[0][r] = 0.f;
      acc[1][r] = 0.f;
    }

    if (g == 0) {
      float sm[4];
#pragma unroll
      for (int r = 0; r < 4; ++r) sm[r] = ig0[r] + ig1[r];
#pragma unroll
      for (int msk = 1; msk < 16; msk <<= 1)
#pragma unroll
        for (int r = 0; r < 4; ++r)
          sm[r] += __shfl_xor(sm[r], msk, 64);
      if (l15 == 0) {
#pragma unroll
        for (int r = 0; r < 4; ++r)
          rsum[quad * 4 + r][cg] = sm[r];
      }
      __syncthreads();
#pragma unroll
      for (int r = 0; r < 4; ++r) {
        const int row = quad * 4 + r;
        const float4 ra = *(const float4*)&rsum[row][0];
        const float4 rb = *(const float4*)&rsum[row][4];
        const float inv = 1.f / (((ra.x + ra.y) + (ra.z + ra.w)) +
                                 ((rb.x + rb.y) + (rb.z + rb.w)));
        ig0[r] *= inv;
        ig1[r] *= inv;
      }
    }
  }

#pragma unroll
  for (int r = 0; r < 4; ++r) {
    const int row = quad * 4 + r;
    const float pr = ps[row];
    const int ci = row * 256 + cg * 32 + l15;
    const size_t base = (size_t)(b0 + row) * 256 + cg * 32 + l15;
    {
      const float cand = fmaf(ig0[r], pr, cs[ci]);
      dout[base] = (1.f - og0[r]) * cand;
      dout[NBV + base] = og0[r] * cand;
    }
    {
      const float cand = fmaf(ig1[r], pr, cs[ci + 16]);
      dout[base + 16] = (1.f - og1[r]) * cand;
      dout[NBV + base + 16] = og1[r] * cand;
    }
  }
}

// ---------------------------------------------------------------- launch
extern "C" void kernel_launch(void* const* d_in, const int* in_sizes, int n_in,
                              void* d_out, int out_size, void* d_ws, size_t ws_size,
                              hipStream_t stream) {
  const float* lc    = (const float*)d_in[0];
  const float* p     = (const float*)d_in[1];
  const float* other = (const float*)d_in[2];
  const float* Wi    = (const float*)d_in[3];
  const float* bi    = (const float*)d_in[4];
  const float* Wr    = (const float*)d_in[5];
  const float* br    = (const float*)d_in[6];
  const float* Wo    = (const float*)d_in[7];
  const float* bo    = (const float*)d_in[8];
  float* out = (float*)d_out;

  char* wsb = (char*)d_ws;
  short* WtB      = (short*)wsb;
  short* featImg  = (short*)(wsb + WTB_BYTES);
  float* cell_sys = (float*)(wsb + WTB_BYTES + FEAT_BYTES);

  k_prep<<<2346, 256, 0, stream>>>(lc, p, other, Wi, Wr, Wo, WtB, featImg, cell_sys);
  k_heavyR9<<<512, 512, 0, stream>>>(featImg, WtB, lc, br, cell_sys);
  k_postR8<<<64, 512, 0, stream>>>(featImg, WtB, bi, bo, p, cell_sys, out);
}

// Round 5
// 212.020 us; speedup vs baseline: 1.2530x; 1.0107x over previous
//
#include <hip/hip_runtime.h>

// MassConservingLSTMCell — round 10: keep B prefetches in flight across the
// per-u barrier. R8/R9 post-mortem: MfmaUtil pinned at ~19% across 3 configs
// (occupancy 20->36% no effect; B volume 2x no effect) => exposed B-load
// latency, re-exposed every u because __syncthreads drains vmcnt(0) 8x/block.
// R10: (1) per-u epilogue barrier = raw s_barrier + lgkmcnt(0) only (LDS
// exchange needs no vmem drain) — B pipeline never drains; (2) dist-2 B
// prefetch (R5's 3-slot flat rotation) on R9's 2-blocks/CU grid; (3) A frags
// read per-c from LDS (no explicit double-buffer; ~120cy LDS latency hides
// under the B window) to keep regs ~128 -> 4 waves/SIMD.
//
// B=1024, U=256, F=31, D=288 (9 k-chunks of 32).

#define EPS_L1 1e-7f

constexpr int BB  = 1024;
constexpr int U   = 256;
constexpr int F   = 31;
constexpr int D   = 1 + U + F;      // 288
constexpr int NBV = BB * U;         // 262144
constexpr int NCH = D / 32;         // 9
constexpr int UIMGB = NCH * 16384;  // 147456 B per u-slice B-image
constexpr size_t WTB_BYTES  = (size_t)258 * UIMGB;
constexpr size_t FEAT_BYTES = (size_t)BB * D * 2;

typedef float f32x4 __attribute__((ext_vector_type(4)));
typedef short bf16x8 __attribute__((ext_vector_type(8)));

__device__ __forceinline__ unsigned f2bf(float x) {
  union { float f; unsigned u; } v; v.f = x;
  unsigned r = v.u + 0x7FFFu + ((v.u >> 16) & 1u);
  return r >> 16;
}

// LDS-only barrier: orders ds ops across the block WITHOUT draining vmcnt —
// in-flight global (B prefetch) loads survive. sched_barrier fences per
// methodology rule #18 (compiler may otherwise hoist consumers past the asm).
__device__ __forceinline__ void barrier_lgkm() {
  asm volatile("s_waitcnt lgkmcnt(0)" ::: "memory");
  __builtin_amdgcn_sched_barrier(0);
  __builtin_amdgcn_s_barrier();
  __builtin_amdgcn_sched_barrier(0);
}

#define GLDS16(gp, lp)                                                        \
  __builtin_amdgcn_global_load_lds(                                          \
      (const __attribute__((address_space(1))) void*)(gp),                   \
      (__attribute__((address_space(3))) void*)(lp), 16, 0, 0)

#define MFMA16(a, b, c) __builtin_amdgcn_mfma_f32_16x16x32_bf16((a), (b), (c), 0, 0, 0)

// ---------------------------------------------------------------- k_prep
// grid 2346 x 256:
//   [0..2322)    weight transform, block = (u, c) single chunk
//   [2322..2338) features -> A fragment images (16 x 64-row)
//   [2338..2346) zero cell_sys (1 MB)
__global__ __launch_bounds__(256) void k_prep(
    const float* __restrict__ lc, const float* __restrict__ p,
    const float* __restrict__ other,
    const float* __restrict__ Wi, const float* __restrict__ Wr,
    const float* __restrict__ Wo,
    short* __restrict__ WtB, short* __restrict__ featImg,
    float* __restrict__ cell_sys) {
  __shared__ unsigned tw[256][17];   // [v][k-pair], odd pitch: <=2-way conflicts
  __shared__ float inv_s[64];
  const int bid = blockIdx.x, t = threadIdx.x;

  if (bid < 2322) {
    // ---- weight transform: one 32k x 256v chunk of u-slice (u = bid/9, c = bid%9)
    const int u = bid / 9, c = bid % 9;
    const float* src; long ld;
    if (u < 256)       { src = Wr + (size_t)u * 256; ld = 65536; }
    else if (u == 256) { src = Wi; ld = 256; }
    else               { src = Wo; ld = 256; }

    // phase 1: coalesced float4 loads of two k-rows, pack k-pairs into u32,
    // transposed stage tw[v][kp]
    const int kp = t >> 4, f = t & 15;           // kp in [0,16), f in [0,16)
    const float* r0 = src + (size_t)(c * 32 + 2 * kp) * ld;
    const float* r1 = r0 + ld;
#pragma unroll
    for (int i = 0; i < 4; ++i) {
      const int v0 = f * 4 + i * 64;
      const float4 a = *(const float4*)(r0 + v0);
      const float4 b = *(const float4*)(r1 + v0);
      tw[v0 + 0][kp] = f2bf(a.x) | (f2bf(b.x) << 16);
      tw[v0 + 1][kp] = f2bf(a.y) | (f2bf(b.y) << 16);
      tw[v0 + 2][kp] = f2bf(a.z) | (f2bf(b.z) << 16);
      tw[v0 + 3][kp] = f2bf(a.w) | (f2bf(b.w) << 16);
    }
    __syncthreads();

    // phase 2: fragment gather — per fragment 4x ds_read_b32 (k-run is
    // contiguous in tw rows) + one 16B store. Layout identical to old WtB.
    const int lane = t & 63, wave = t >> 6;
    const int g = lane >> 4, l15 = lane & 15;
    short* dst = WtB + (size_t)u * 73728 + (size_t)c * 16 * 512;
#pragma unroll
    for (int ii = 0; ii < 4; ++ii) {
      const int n0 = wave * 4 + ii;
      const int row = n0 * 16 + l15;
      union { unsigned u4[4]; bf16x8 h; } cv;
#pragma unroll
      for (int j = 0; j < 4; ++j) cv.u4[j] = tw[row][g * 4 + j];
      *(bf16x8*)(dst + (size_t)n0 * 512 + lane * 8) = cv.h;
    }
  } else if (bid < 2338) {
    // ---- features -> A fragment image (64-row block mb)
    const int mb = bid - 2322;
    const int b0 = mb * 64;
    const int row = t >> 2, q = t & 3;
    const float4* lp = (const float4*)(lc + (size_t)(b0 + row) * 256 + q * 64);
    float s = 0.f;
#pragma unroll
    for (int j = 0; j < 16; ++j) {
      const float4 v = lp[j];
      s += fabsf(v.x) + fabsf(v.y) + fabsf(v.z) + fabsf(v.w);
    }
    s += __shfl_xor(s, 1, 64);
    s += __shfl_xor(s, 2, 64);
    if (q == 0) inv_s[row] = 1.f / (s + EPS_L1);
    __syncthreads();
#pragma unroll
    for (int i = 0; i < 9; ++i) {
      const int idx = i * 256 + t;
      const int reg = idx >> 6, l = idx & 63;
      const int c = reg >> 2, mt = reg & 3;
      const int lrow = mt * 16 + (l & 15);
      const int grow = b0 + lrow;
      const int k0 = c * 32 + (l >> 4) * 8;
      bf16x8 h;
#pragma unroll
      for (int j = 0; j < 8; ++j) {
        const int k = k0 + j;
        float v;
        if (k == 0) v = p[grow];
        else if (k <= 256) v = lc[(size_t)grow * 256 + (k - 1)] * inv_s[lrow];
        else v = other[(size_t)grow * 31 + (k - 257)];
        h[j] = (short)f2bf(v);
      }
      *(bf16x8*)(featImg + (size_t)mb * 18432 + (size_t)reg * 512 + l * 8) = h;
    }
  } else {
    // ---- zero cell_sys (1 MB)
    float4* cs4 = (float4*)cell_sys;
    const int base = (bid - 2338) * 8192 + t;
    const float4 z = {0.f, 0.f, 0.f, 0.f};
#pragma unroll
    for (int k2 = 0; k2 < 32; ++k2) cs4[base + k2 * 256] = z;
  }
}

// ---------------------------------------------------------------- k_heavyR10
// 512 blocks (16 Mb x 32 ug), 512 thr, 8 waves = 2 rh x 4 cq,
// wave tile 2mt x 4nt, dist-2 B prefetch (3-slot flat rotation),
// LDS-only per-u barrier (vmcnt pipeline never drains), 2 blocks/CU.
__global__ __launch_bounds__(512, 4) void k_heavyR10(
    const short* __restrict__ featImg, const short* __restrict__ WtB,
    const float* __restrict__ lc, const float* __restrict__ br,
    float* __restrict__ cell_sys) {
  __shared__ short aT[18432];          // 36864 B: [c][mt][1KB], one 64-row image
  __shared__ float rsum[2][64][4];     // [par][row][cq]
  __shared__ float lcs[8][64];         // [uu][row]

  const int t = threadIdx.x, lane = t & 63, wave = t >> 6;
  const int cq = wave & 3, rh = wave >> 2;
  const int quad = lane >> 4, l15 = lane & 15;
  const int bid = blockIdx.x;
  const int Mb = bid >> 5, ug = bid & 31;   // bid%8 = ug%8 = XCD pin
  const int b0 = Mb * 64, u0 = ug * 8;

  // stage A (one 64-row image, linear; guard is wave-uniform: t<256)
  {
    const char* gA = (const char*)featImg + (size_t)Mb * 36864;
    char* lA = (char*)aT;
#pragma unroll
    for (int i = 0; i < 5; ++i) {
      const int off = i * 8192 + t * 16;
      if (off < 36864) GLDS16(gA + off, lA + off);
    }
  }

  // lc hoist: 8 contiguous floats per row, once.
  if (t < 64) {
    const float* lp = lc + (size_t)(b0 + t) * 256 + u0;
    const float4 v0 = *(const float4*)(lp);
    const float4 v1 = *(const float4*)(lp + 4);
    lcs[0][t] = v0.x; lcs[1][t] = v0.y; lcs[2][t] = v0.z; lcs[3][t] = v0.w;
    lcs[4][t] = v1.x; lcs[5][t] = v1.y; lcs[6][t] = v1.z; lcs[7][t] = v1.w;
  }

  // fragment base addresses:
  //   A frag (c, m): aT + rh*2048 + c*4096 + m*1024 + lane*16   (m = 0..1)
  //   B frag (c, n): WtB[u] + cq*4096 + c*16384 + n*1024 + lane*16
  const char* aB = (const char*)aT + rh * 2048 + lane * 16;
  const char* bB = (const char*)WtB + (size_t)u0 * UIMGB + cq * 4096 + lane * 16;

  f32x4 acc[2][4], outa[2][4];
#pragma unroll
  for (int m = 0; m < 2; ++m)
#pragma unroll
    for (int n = 0; n < 4; ++n)
#pragma unroll
      for (int r = 0; r < 4; ++r) { acc[m][n][r] = 0.f; outa[m][n][r] = 0.f; }

  // B distance-2 prefetch: 3-slot static rotation (flat across u images)
  bf16x8 bfr[3][4];
#pragma unroll
  for (int n = 0; n < 4; ++n) bfr[0][n] = *(const bf16x8*)(bB + n * 1024);
#pragma unroll
  for (int n = 0; n < 4; ++n) bfr[1][n] = *(const bf16x8*)(bB + 16384 + n * 1024);

  __syncthreads();   // A + lcs resident (drains the 2 B groups once; data kept)

  for (int uu = 0; uu < 8; ++uu) {
    const int u = u0 + uu;
    float bv[4];

#pragma unroll
    for (int c = 0; c < 9; ++c) {
      if (c == 0) {
#pragma unroll
        for (int n = 0; n < 4; ++n)
          bv[n] = br[(size_t)u * 256 + cq * 64 + n * 16 + l15];
      }
      // B prefetch c+2 (flat; crosses into u+1's image at c>=7)
#pragma unroll
      for (int n = 0; n < 4; ++n)
        bfr[(c + 2) % 3][n] = *(const bf16x8*)(bB + (c + 2) * 16384 + n * 1024);
      // A frags for this c: direct LDS reads (compiler schedules/early-hoists)
      const bf16x8 a0 = *(const bf16x8*)(aB + c * 4096);
      const bf16x8 a1 = *(const bf16x8*)(aB + c * 4096 + 1024);
#pragma unroll
      for (int n = 0; n < 4; ++n) {
        acc[0][n] = MFMA16(a0, bfr[c % 3][n], acc[0][n]);
        acc[1][n] = MFMA16(a1, bfr[c % 3][n], acc[1][n]);
      }
    }
    bB += UIMGB;

    // ---- epilogue for u: bias+relu (into acc), cross-wave rownorm, accumulate
    const int ub = uu & 1;
    float sm[2][4];
#pragma unroll
    for (int m = 0; m < 2; ++m)
#pragma unroll
      for (int r = 0; r < 4; ++r) {
        float sv = 0.f;
#pragma unroll
        for (int n = 0; n < 4; ++n) {
          const float rv = fmaxf(acc[m][n][r] + bv[n], 0.f);
          acc[m][n][r] = rv;
          sv += rv;
        }
        sm[m][r] = sv;
      }
#pragma unroll
    for (int msk = 1; msk < 16; msk <<= 1)
#pragma unroll
      for (int m = 0; m < 2; ++m)
#pragma unroll
        for (int r = 0; r < 4; ++r)
          sm[m][r] += __shfl_xor(sm[m][r], msk, 64);
    if (l15 == 0) {
#pragma unroll
      for (int m = 0; m < 2; ++m)
#pragma unroll
        for (int r = 0; r < 4; ++r)
          rsum[ub][rh * 32 + m * 16 + quad * 4 + r][cq] = sm[m][r];
    }
    // LDS-only barrier: B prefetches (vmem) stay in flight across u boundary.
    barrier_lgkm();
#pragma unroll
    for (int m = 0; m < 2; ++m)
#pragma unroll
      for (int r = 0; r < 4; ++r) {
        const int row = rh * 32 + m * 16 + quad * 4 + r;
        const float4 rv = *(const float4*)&rsum[ub][row][0];
        const float tot = (rv.x + rv.y) + (rv.z + rv.w);
        const float alpha = lcs[uu][row] * __builtin_amdgcn_rcpf(tot);
#pragma unroll
        for (int n = 0; n < 4; ++n) {
          outa[m][n][r] = fmaf(alpha, acc[m][n][r], outa[m][n][r]);
          acc[m][n][r] = 0.f;
        }
      }
  }

#pragma unroll
  for (int m = 0; m < 2; ++m)
#pragma unroll
    for (int r = 0; r < 4; ++r) {
      const int grow = b0 + rh * 32 + m * 16 + quad * 4 + r;
#pragma unroll
      for (int n = 0; n < 4; ++n)
        atomicAdd(&cell_sys[(size_t)grow * 256 + cq * 64 + n * 16 + l15],
                  outa[m][n][r]);
    }
}

// ---------------------------------------------------------------- k_postR8
// 64 blocks x 512 thr: 16 rows each. cell_sys tile -> LDS, gates MFMA
// (ig,og in regs) + final combine.
__global__ __launch_bounds__(512, 2) void k_postR8(
    const short* __restrict__ featImg, const short* __restrict__ WtB,
    const float* __restrict__ bi, const float* __restrict__ bo,
    const float* __restrict__ p, const float* __restrict__ cell_sys,
    float* __restrict__ dout) {
  __shared__ short aT9[9 * 512];       // 9 KB: A fragments (c=0..8) for 16 rows
  __shared__ float cs[16 * 256];       // 16 KB: cell_sys tile
  __shared__ float rsum[16][12];
  __shared__ float ps[16];

  const int t = threadIdx.x, lane = t & 63, cg = t >> 6;
  const int quad = lane >> 4, l15 = lane & 15;
  const int mb16 = blockIdx.x, b0 = mb16 * 16;
  const int mb = mb16 >> 2, mt = mb16 & 3;

  // stage A fragments: regs (c*4 + mt), c = 0..8  -> aT9[c*1024B]
  {
    const char* gsrc = (const char*)featImg + (size_t)mb * 36864 + mt * 1024;
    char* ldst = (char*)aT9;
    GLDS16(gsrc + (size_t)(t >> 6) * 4096 + (t & 63) * 16, ldst + t * 16);
    if (t < 64)
      GLDS16(gsrc + (size_t)8 * 4096 + t * 16, ldst + 8192 + t * 16);
  }
  if (t < 16) ps[t] = p[b0 + t];

  // copy cell_sys rows [b0, b0+16) into cs
  {
    const f32x4* pp = (const f32x4*)(cell_sys + (size_t)b0 * 256);
    ((f32x4*)cs)[t] = pp[t];
    ((f32x4*)cs)[512 + t] = pp[512 + t];
  }

  f32x4 acc[2];
#pragma unroll
  for (int n = 0; n < 2; ++n)
#pragma unroll
    for (int r = 0; r < 4; ++r) acc[n][r] = 0.f;

  const char* bptr = (const char*)WtB + (size_t)256 * UIMGB + cg * 2048 + lane * 16;
  bf16x8 cb0 = *(const bf16x8*)(bptr);
  bf16x8 cb1 = *(const bf16x8*)(bptr + 1024);
  bf16x8 nb0 = *(const bf16x8*)(bptr + 16384);
  bf16x8 nb1 = *(const bf16x8*)(bptr + 16384 + 1024);
  bptr += 32768;

  __syncthreads();   // A fragments + cs resident

  float ig0[4], ig1[4], og0[4], og1[4];

#pragma unroll
  for (int g = 0; g < 2; ++g) {
    const float* bias = (g == 0) ? bi : bo;
    const float bv0 = bias[cg * 32 + l15];
    const float bv1 = bias[cg * 32 + 16 + l15];
#pragma unroll
    for (int c = 0; c < 9; ++c) {
      const bf16x8 pb0 = *(const bf16x8*)(bptr);
      const bf16x8 pb1 = *(const bf16x8*)(bptr + 1024);
      bptr += 16384;
      const bf16x8 a0 = *(const bf16x8*)((const char*)aT9 + c * 1024 + lane * 16);
      acc[0] = MFMA16(a0, cb0, acc[0]);
      acc[1] = MFMA16(a0, cb1, acc[1]);
      cb0 = nb0; cb1 = nb1; nb0 = pb0; nb1 = pb1;
    }

#pragma unroll
    for (int r = 0; r < 4; ++r) {
      const float v0 = 1.f / (1.f + __expf(-(acc[0][r] + bv0)));
      const float v1 = 1.f / (1.f + __expf(-(acc[1][r] + bv1)));
      if (g == 0) { ig0[r] = v0; ig1[r] = v1; }
      else        { og0[r] = v0; og1[r] = v1; }
      acc[0][r] = 0.f;
      acc[1][r] = 0.f;
    }

    if (g == 0) {
      float sm[4];
#pragma unroll
      for (int r = 0; r < 4; ++r) sm[r] = ig0[r] + ig1[r];
#pragma unroll
      for (int msk = 1; msk < 16; msk <<= 1)
#pragma unroll
        for (int r = 0; r < 4; ++r)
          sm[r] += __shfl_xor(sm[r], msk, 64);
      if (l15 == 0) {
#pragma unroll
        for (int r = 0; r < 4; ++r)
          rsum[quad * 4 + r][cg] = sm[r];
      }
      __syncthreads();
#pragma unroll
      for (int r = 0; r < 4; ++r) {
        const int row = quad * 4 + r;
        const float4 ra = *(const float4*)&rsum[row][0];
        const float4 rb = *(const float4*)&rsum[row][4];
        const float inv = 1.f / (((ra.x + ra.y) + (ra.z + ra.w)) +
                                 ((rb.x + rb.y) + (rb.z + rb.w)));
        ig0[r] *= inv;
        ig1[r] *= inv;
      }
    }
  }

#pragma unroll
  for (int r = 0; r < 4; ++r) {
    const int row = quad * 4 + r;
    const float pr = ps[row];
    const int ci = row * 256 + cg * 32 + l15;
    const size_t base = (size_t)(b0 + row) * 256 + cg * 32 + l15;
    {
      const float cand = fmaf(ig0[r], pr, cs[ci]);
      dout[base] = (1.f - og0[r]) * cand;
      dout[NBV + base] = og0[r] * cand;
    }
    {
      const float cand = fmaf(ig1[r], pr, cs[ci + 16]);
      dout[base + 16] = (1.f - og1[r]) * cand;
      dout[NBV + base + 16] = og1[r] * cand;
    }
  }
}

// ---------------------------------------------------------------- launch
extern "C" void kernel_launch(void* const* d_in, const int* in_sizes, int n_in,
                              void* d_out, int out_size, void* d_ws, size_t ws_size,
                              hipStream_t stream) {
  const float* lc    = (const float*)d_in[0];
  const float* p     = (const float*)d_in[1];
  const float* other = (const float*)d_in[2];
  const float* Wi    = (const float*)d_in[3];
  const float* bi    = (const float*)d_in[4];
  const float* Wr    = (const float*)d_in[5];
  const float* br    = (const float*)d_in[6];
  const float* Wo    = (const float*)d_in[7];
  const float* bo    = (const float*)d_in[8];
  float* out = (float*)d_out;

  char* wsb = (char*)d_ws;
  short* WtB      = (short*)wsb;
  short* featImg  = (short*)(wsb + WTB_BYTES);
  float* cell_sys = (float*)(wsb + WTB_BYTES + FEAT_BYTES);

  k_prep<<<2346, 256, 0, stream>>>(lc, p, other, Wi, Wr, Wo, WtB, featImg, cell_sys);
  k_heavyR10<<<512, 512, 0, stream>>>(featImg, WtB, lc, br, cell_sys);
  k_postR8<<<64, 512, 0, stream>>>(featImg, WtB, bi, bo, p, cell_sys, out);
}